// Round 11
// baseline (263.986 us; speedup 1.0000x reference)
//
#include <hip/hip_runtime.h>

#define N_NODES 50000
#define N_EDGES 800000
#define NBLK_SCAN ((N_NODES + 255) / 256)   // 196
#define CVT_B 6250                          // N_NODES*32/256
#define HIST_B 3125                         // N_EDGES/256
#define NODE_B ((N_NODES + 63) / 64)        // 782
#define EDGE_B (N_EDGES / 128)              // 6250
#define G12_B 25000                         // split gathers: 2 halves x 12500

typedef _Float16 h2 __attribute__((ext_vector_type(2)));
typedef _Float16 f16x8 __attribute__((ext_vector_type(8)));
typedef float f32x4 __attribute__((ext_vector_type(4)));

__device__ __forceinline__ float sigf(float v) {
  return __builtin_amdgcn_rcpf(1.0f + __expf(-v));
}
__device__ __forceinline__ unsigned packh2(float a, float b) {
  return __builtin_bit_cast(unsigned, __builtin_amdgcn_cvt_pkrtz(a, b));
}
__device__ __forceinline__ float2 unpackh2(unsigned u) {
  h2 p = __builtin_bit_cast(h2, u);
  return make_float2((float)p.x, (float)p.y);
}
__device__ __forceinline__ void acc8(float* a, uint4 v) {
  float2 p0 = unpackh2(v.x), p1 = unpackh2(v.y);
  float2 p2 = unpackh2(v.z), p3 = unpackh2(v.w);
  a[0] += p0.x; a[1] += p0.y; a[2] += p1.x; a[3] += p1.y;
  a[4] += p2.x; a[5] += p2.y; a[6] += p3.x; a[7] += p3.y;
}
__device__ __forceinline__ unsigned addpk(unsigned a, unsigned b) {
  h2 r = __builtin_bit_cast(h2, a) + __builtin_bit_cast(h2, b);
  return __builtin_bit_cast(unsigned, r);
}
#define MFMA16(A, B, C) __builtin_amdgcn_mfma_f32_16x16x32_f16(A, __builtin_bit_cast(f16x8, B), C, 0, 0, 0)

// ---- prep: x->f16 SPLIT table | dst histogram | weights -> MFMA B-frag ----
__global__ __launch_bounds__(256) void prep_kernel(
    const float* __restrict__ x, unsigned* __restrict__ X16s,
    const int* __restrict__ dst, int* __restrict__ cnt,
    const float* __restrict__ Wn1, const float* __restrict__ Wn2,
    const float* __restrict__ Wc1, const float* __restrict__ Wn3,
    const float* __restrict__ Wc2, const float* __restrict__ Wg1,
    uint4* __restrict__ Wn1f, uint4* __restrict__ Wn2f, uint4* __restrict__ Wc1f,
    uint4* __restrict__ Wn3f, uint4* __restrict__ Wc2f, uint4* __restrict__ Wg1f)
{
  int b = blockIdx.x;
  if (b < CVT_B) {
    int i = b * 256 + threadIdx.x;          // uint index: n*32 + c
    int n = i >> 5, c = i & 31;
    float2 v = ((const float2*)x)[i];
    int half = c >> 4;
    X16s[((size_t)half * N_NODES + n) * 16 + (c & 15)] = packh2(v.x, v.y);
  } else if (b < CVT_B + HIST_B) {
    int e = (b - CVT_B) * 256 + threadIdx.x;
    atomicAdd(&cnt[dst[e]], 1);
  } else {
    int lane = threadIdx.x & 63, w = threadIdx.x >> 6;
    int n15 = lane & 15, chunk = lane >> 4;
    if (w == 0) {           // Wn1f: K=64, N=128 -> 8 nt x 2 ks
#pragma unroll
      for (int f = 0; f < 16; ++f) {
        int nt = f >> 1, ks = f & 1;
        int n = nt * 16 + n15;
        f16x8 vv;
#pragma unroll
        for (int i = 0; i < 8; ++i) vv[i] = (_Float16)Wn1[(ks * 32 + chunk * 8 + i) * 128 + n];
        Wn1f[f * 64 + lane] = __builtin_bit_cast(uint4, vv);
      }
    } else if (w == 1) {    // Wn2f: K=128, N=64 -> 4 nt x 4 ks
#pragma unroll
      for (int f = 0; f < 16; ++f) {
        int nt = f >> 2, ks = f & 3;
        int n = nt * 16 + n15;
        f16x8 vv;
#pragma unroll
        for (int i = 0; i < 8; ++i) vv[i] = (_Float16)Wn2[(ks * 32 + chunk * 8 + i) * 64 + n];
        Wn2f[f * 64 + lane] = __builtin_bit_cast(uint4, vv);
      }
    } else if (w == 2) {    // Wc1f: K=128, N=64 -> 4 nt x 4 ks
#pragma unroll
      for (int f = 0; f < 16; ++f) {
        int nt = f >> 2, ks = f & 3;
        int n = nt * 16 + n15;
        f16x8 vv;
#pragma unroll
        for (int i = 0; i < 8; ++i) vv[i] = (_Float16)Wc1[(ks * 32 + chunk * 8 + i) * 64 + n];
        Wc1f[f * 64 + lane] = __builtin_bit_cast(uint4, vv);
      }
    } else {                // Wn3f, Wc2f: K=64,N=32; Wg1f
#pragma unroll
      for (int f = 0; f < 4; ++f) {
        int nt = f >> 1, ks = f & 1;
        int n = nt * 16 + n15;
        f16x8 v3, vc;
#pragma unroll
        for (int i = 0; i < 8; ++i) {
          int k = ks * 32 + chunk * 8 + i;
          v3[i] = (_Float16)Wn3[k * 32 + n];
          vc[i] = (_Float16)Wc2[k * 32 + n];
        }
        Wn3f[f * 64 + lane] = __builtin_bit_cast(uint4, v3);
        Wc2f[f * 64 + lane] = __builtin_bit_cast(uint4, vc);
      }
#pragma unroll
      for (int ks = 0; ks < 2; ++ks)
#pragma unroll
        for (int nh = 0; nh < 2; ++nh) {
          f16x8 vv;
#pragma unroll
          for (int i = 0; i < 8; ++i)
            vv[i] = (_Float16)Wg1[(ks * 32 + chunk * 8 + i) * 32 + nh * 16 + n15];
          Wg1f[(ks * 2 + nh) * 64 + lane] = __builtin_bit_cast(uint4, vv);
        }
    }
  }
}

// ---- scan1: per-block sums ----
__global__ __launch_bounds__(256) void scan1_kernel(
    const int* __restrict__ cnt, int* __restrict__ bsum)
{
  int i = blockIdx.x * 256 + threadIdx.x;
  int v = (i < N_NODES) ? cnt[i] : 0;
#pragma unroll
  for (int off = 32; off; off >>= 1) v += __shfl_xor(v, off);
  __shared__ int ws[4];
  if ((threadIdx.x & 63) == 0) ws[threadIdx.x >> 6] = v;
  __syncthreads();
  if (threadIdx.x == 0) bsum[blockIdx.x] = ws[0] + ws[1] + ws[2] + ws[3];
}

// ---- scan3 (scan2 folded in) + did-expand ----
__global__ __launch_bounds__(256) void scan3_kernel(
    const int* __restrict__ cnt, const int* __restrict__ bsum,
    int* __restrict__ rowptr, int* __restrict__ cursor,
    int* __restrict__ did)
{
  int tid = threadIdx.x, lane = tid & 63, w = tid >> 6;
  __shared__ int ws[4], ws2[4];
  int bv = (tid < blockIdx.x) ? bsum[tid] : 0;   // NBLK_SCAN <= 256
  int s = bv;
#pragma unroll
  for (int off = 32; off; off >>= 1) s += __shfl_xor(s, off);
  if (lane == 0) ws2[w] = s;
  int i = blockIdx.x * 256 + tid;
  int v = (i < N_NODES) ? cnt[i] : 0;
  int x = v;
#pragma unroll
  for (int off = 1; off < 64; off <<= 1) {
    int y = __shfl_up(x, off);
    if (lane >= off) x += y;
  }
  if (lane == 63) ws[w] = x;
  __syncthreads();
  int woff = ws2[0] + ws2[1] + ws2[2] + ws2[3];
#pragma unroll
  for (int k = 0; k < 4; ++k) if (k < w) woff += ws[k];
  if (i < N_NODES) {
    int excl = woff + x - v;
    cursor[i] = excl;
    rowptr[i + 1] = excl + v;
    if (i == 0) rowptr[0] = 0;
    for (int k = 0; k < v; ++k) did[excl + k] = i;
  }
}

// ---- fill: one packed uint2 {src, edge-id} per CSR slot ----
__global__ __launch_bounds__(256) void fill_kernel(
    const int* __restrict__ src, const int* __restrict__ dst,
    int* __restrict__ cursor, uint2* __restrict__ ce)
{
  int e = blockIdx.x * 256 + threadIdx.x;
  if (e >= N_EDGES) return;
  int pos = atomicAdd(&cursor[dst[e]], 1);
  ce[pos] = make_uint2((unsigned)src[e], (unsigned)e);
}

// ---- gather1 (split): T16s[h][n] = X16s[h][n] + sum X16s[h][src]; 16 e/iter ----
__global__ __launch_bounds__(256) void gather1_kernel(
    const unsigned* __restrict__ X16s, const int* __restrict__ rowptr,
    const int* __restrict__ ce2, unsigned* __restrict__ T16s)
{
  int bid = blockIdx.x;
  int slot = bid & 7, half = slot >> 2;
  int grp = (bid >> 3) * 4 + (slot & 3);      // 0..12499
  int w = threadIdx.x >> 6, lane = threadIdx.x & 63;
  int n = grp * 4 + w;
  int beg = rowptr[n], end = rowptr[n + 1];
  int q = lane >> 2, c = lane & 3;
  const uint4* feat4 = (const uint4*)X16s + (size_t)half * N_NODES * 4;
  float a[8] = {0.f, 0.f, 0.f, 0.f, 0.f, 0.f, 0.f, 0.f};
  for (int k0 = beg; k0 < end; k0 += 64) {
    int kk = k0 + lane;
    int cv = (kk < end) ? ce2[2 * kk] : 0;
    int m = end - k0; if (m > 64) m = 64;
    int e = 0;
#pragma unroll 2
    for (; e + 15 < m; e += 16) {
      int se = __shfl(cv, e + q);
      acc8(a, feat4[(size_t)se * 4 + c]);
    }
    int r = m - e;
    if (r) {
      int idx = e + q; if (idx >= m) idx = m - 1;
      int se = __shfl(cv, idx);
      uint4 v = feat4[(size_t)se * 4 + c];
      if (q < r) acc8(a, v);
    }
  }
#pragma unroll
  for (int j = 0; j < 8; ++j) {
    a[j] += __shfl_xor(a[j], 32);
    a[j] += __shfl_xor(a[j], 16);
    a[j] += __shfl_xor(a[j], 8);
    a[j] += __shfl_xor(a[j], 4);
  }
  if (q == 0) {
    uint4 xv = feat4[(size_t)n * 4 + c];
    float2 x0 = unpackh2(xv.x), x1 = unpackh2(xv.y);
    float2 x2 = unpackh2(xv.z), x3 = unpackh2(xv.w);
    uint4 o;
    o.x = packh2(a[0] + x0.x, a[1] + x0.y);
    o.y = packh2(a[2] + x1.x, a[3] + x1.y);
    o.z = packh2(a[4] + x2.x, a[5] + x2.y);
    o.w = packh2(a[6] + x3.x, a[7] + x3.y);
    ((uint4*)T16s)[((size_t)half * N_NODES + n) * 4 + c] = o;
  }
}

// ---- gather2 (split): H2[n] cols[h*32..h*32+32) = sig(Q2s[h][n] + sum + bn2) ----
__global__ __launch_bounds__(256) void gather2_kernel(
    const unsigned* __restrict__ Q2s, const int* __restrict__ rowptr,
    const int* __restrict__ ce2, const float* __restrict__ bn2,
    unsigned* __restrict__ H2)
{
  int bid = blockIdx.x;
  int slot = bid & 7, half = slot >> 2;
  int grp = (bid >> 3) * 4 + (slot & 3);
  int w = threadIdx.x >> 6, lane = threadIdx.x & 63;
  int n = grp * 4 + w;
  int beg = rowptr[n], end = rowptr[n + 1];
  int q = lane >> 2, c = lane & 3;
  const uint4* feat4 = (const uint4*)Q2s + (size_t)half * N_NODES * 4;
  float a[8] = {0.f, 0.f, 0.f, 0.f, 0.f, 0.f, 0.f, 0.f};
  for (int k0 = beg; k0 < end; k0 += 64) {
    int kk = k0 + lane;
    int cv = (kk < end) ? ce2[2 * kk] : 0;
    int m = end - k0; if (m > 64) m = 64;
    int e = 0;
#pragma unroll 2
    for (; e + 15 < m; e += 16) {
      int se = __shfl(cv, e + q);
      acc8(a, feat4[(size_t)se * 4 + c]);
    }
    int r = m - e;
    if (r) {
      int idx = e + q; if (idx >= m) idx = m - 1;
      int se = __shfl(cv, idx);
      uint4 v = feat4[(size_t)se * 4 + c];
      if (q < r) acc8(a, v);
    }
  }
#pragma unroll
  for (int j = 0; j < 8; ++j) {
    a[j] += __shfl_xor(a[j], 32);
    a[j] += __shfl_xor(a[j], 16);
    a[j] += __shfl_xor(a[j], 8);
    a[j] += __shfl_xor(a[j], 4);
  }
  if (q == 0) {
    uint4 qv = feat4[(size_t)n * 4 + c];
    float4 bnA = ((const float4*)bn2)[half * 8 + 2 * c];
    float4 bnB = ((const float4*)bn2)[half * 8 + 2 * c + 1];
    float2 q0 = unpackh2(qv.x), q1 = unpackh2(qv.y);
    float2 q2 = unpackh2(qv.z), q3 = unpackh2(qv.w);
    uint4 o;
    o.x = packh2(sigf(a[0] + q0.x + bnA.x), sigf(a[1] + q0.y + bnA.y));
    o.y = packh2(sigf(a[2] + q1.x + bnA.z), sigf(a[3] + q1.y + bnA.w));
    o.z = packh2(sigf(a[4] + q2.x + bnB.x), sigf(a[5] + q2.y + bnB.y));
    o.w = packh2(sigf(a[6] + q3.x + bnB.z), sigf(a[7] + q3.y + bnB.w));
    ((uint4*)H2)[(size_t)n * 8 + half * 4 + c] = o;
  }
}

// ---- gather3 + node3 fused: 16 edges/iter (Q3 1.6MB: already L2-resident) ----
__global__ __launch_bounds__(256) void gather3_kernel(
    const unsigned* __restrict__ Q3u, const int* __restrict__ rowptr,
    const int* __restrict__ ce2, const float* __restrict__ bn3,
    const float* __restrict__ Wc3, _Float16* __restrict__ P3h)
{
  int w = threadIdx.x >> 6, lane = threadIdx.x & 63;
  int n = blockIdx.x * 4 + w;
  if (n >= N_NODES) return;
  int beg = rowptr[n], end = rowptr[n + 1];
  int q = lane >> 2, c = lane & 3;
  const uint4* feat4 = (const uint4*)Q3u;
  float a[8] = {0.f, 0.f, 0.f, 0.f, 0.f, 0.f, 0.f, 0.f};
  for (int k0 = beg; k0 < end; k0 += 64) {
    int kk = k0 + lane;
    int cv = (kk < end) ? ce2[2 * kk] : 0;
    int m = end - k0; if (m > 64) m = 64;
    int e = 0;
#pragma unroll 2
    for (; e + 15 < m; e += 16) {
      int se = __shfl(cv, e + q);
      acc8(a, feat4[(size_t)se * 4 + c]);
    }
    int r = m - e;
    if (r) {
      int idx = e + q; if (idx >= m) idx = m - 1;
      int se = __shfl(cv, idx);
      uint4 v = feat4[(size_t)se * 4 + c];
      if (q < r) acc8(a, v);
    }
  }
#pragma unroll
  for (int j = 0; j < 8; ++j) {
    a[j] += __shfl_xor(a[j], 32);
    a[j] += __shfl_xor(a[j], 16);
    a[j] += __shfl_xor(a[j], 8);
    a[j] += __shfl_xor(a[j], 4);
  }
  if (q == 0) {
    uint4 qv = feat4[(size_t)n * 4 + c];
    float4 bnA = ((const float4*)bn3)[2 * c], bnB = ((const float4*)bn3)[2 * c + 1];
    float4 wcA = ((const float4*)Wc3)[2 * c], wcB = ((const float4*)Wc3)[2 * c + 1];
    float2 q0 = unpackh2(qv.x), q1 = unpackh2(qv.y);
    float2 q2 = unpackh2(qv.z), q3 = unpackh2(qv.w);
    float p = sigf(a[0] + q0.x + bnA.x) * wcA.x + sigf(a[1] + q0.y + bnA.y) * wcA.y
            + sigf(a[2] + q1.x + bnA.z) * wcA.z + sigf(a[3] + q1.y + bnA.w) * wcA.w
            + sigf(a[4] + q2.x + bnB.x) * wcB.x + sigf(a[5] + q2.y + bnB.y) * wcB.y
            + sigf(a[6] + q3.x + bnB.z) * wcB.z + sigf(a[7] + q3.y + bnB.w) * wcB.w;
    p += __shfl_xor(p, 1); p += __shfl_xor(p, 2);
    if (c == 0) P3h[n] = (_Float16)p;
  }
}

// ---- node layer 1 (MFMA): T16s (split) -> h1 -> Q2s (split), P1 (normal) ----
__global__ __launch_bounds__(256) void node1_kernel(
    const unsigned* __restrict__ T16s,
    const uint4* __restrict__ Wn1f, const uint4* __restrict__ Wn2f,
    const uint4* __restrict__ Wc1f, const float* __restrict__ bn1,
    _Float16* __restrict__ Q2s, _Float16* __restrict__ P1h)
{
  __shared__ __align__(16) _Float16 t_lds[64 * 72];
  __shared__ __align__(16) _Float16 h1_lds[64 * 136];
  int tid = threadIdx.x;
  int lane = tid & 63, w = tid >> 6;
  int nbase = blockIdx.x * 64;

#pragma unroll
  for (int rep = 0; rep < 2; ++rep) {
    int uidx = rep * 1024 + tid * 4;
    int node = uidx >> 5, c = uidx & 31;
    int gn = nbase + node; if (gn > N_NODES - 1) gn = N_NODES - 1;
    int half = c >> 4, off = (c & 15) >> 2;
    uint4 tv = ((const uint4*)T16s)[((size_t)half * N_NODES + gn) * 4 + off];
    *(uint4*)(t_lds + node * 72 + c * 2) = tv;
  }
  __syncthreads();

  int row16 = lane & 15, chunk = lane >> 4;
  uint4 b1[2][2];
#pragma unroll
  for (int ntl = 0; ntl < 2; ++ntl)
#pragma unroll
    for (int ks = 0; ks < 2; ++ks)
      b1[ntl][ks] = Wn1f[((2 * w + ntl) * 2 + ks) * 64 + lane];

  f32x4 acc[4][2];
#pragma unroll
  for (int mt = 0; mt < 4; ++mt)
#pragma unroll
    for (int ntl = 0; ntl < 2; ++ntl) acc[mt][ntl] = (f32x4){0.f, 0.f, 0.f, 0.f};
#pragma unroll
  for (int mt = 0; mt < 4; ++mt) {
    const _Float16* ab = t_lds + (mt * 16 + row16) * 72 + chunk * 8;
    f16x8 A0 = *(const f16x8*)ab;
    f16x8 A1 = *(const f16x8*)(ab + 32);
#pragma unroll
    for (int ntl = 0; ntl < 2; ++ntl) {
      acc[mt][ntl] = MFMA16(A0, b1[ntl][0], acc[mt][ntl]);
      acc[mt][ntl] = MFMA16(A1, b1[ntl][1], acc[mt][ntl]);
    }
  }
  float bnv0 = bn1[w * 32 + row16], bnv1 = bn1[w * 32 + 16 + row16];
#pragma unroll
  for (int mt = 0; mt < 4; ++mt)
#pragma unroll
    for (int r = 0; r < 4; ++r) {
      int rowl = mt * 16 + chunk * 4 + r;
      h1_lds[rowl * 136 + w * 32 + row16]      = (_Float16)sigf(acc[mt][0][r] + bnv0);
      h1_lds[rowl * 136 + w * 32 + 16 + row16] = (_Float16)sigf(acc[mt][1][r] + bnv1);
    }
  __syncthreads();

#pragma unroll
  for (int job = 0; job < 2; ++job) {
    const uint4* Wf = job ? Wc1f : Wn2f;
    uint4 bf[4];
#pragma unroll
    for (int ks = 0; ks < 4; ++ks) bf[ks] = Wf[(w * 4 + ks) * 64 + lane];
    f32x4 a2[4];
#pragma unroll
    for (int mt = 0; mt < 4; ++mt) a2[mt] = (f32x4){0.f, 0.f, 0.f, 0.f};
#pragma unroll
    for (int mt = 0; mt < 4; ++mt) {
      const _Float16* hb = h1_lds + (mt * 16 + row16) * 136 + chunk * 8;
#pragma unroll
      for (int ks = 0; ks < 4; ++ks) {
        f16x8 A = *(const f16x8*)(hb + ks * 32);
        a2[mt] = MFMA16(A, bf[ks], a2[mt]);
      }
    }
#pragma unroll
    for (int mt = 0; mt < 4; ++mt)
#pragma unroll
      for (int r = 0; r < 4; ++r) {
        int gn = nbase + mt * 16 + chunk * 4 + r;
        if (gn < N_NODES) {
          if (job) {   // P1: normal [N][64]
            P1h[(size_t)gn * 64 + w * 16 + row16] = (_Float16)a2[mt][r];
          } else {     // Q2: split [2][N][32]
            int half = w >> 1, colh = (w & 1) * 16 + row16;
            Q2s[((size_t)half * N_NODES + gn) * 32 + colh] = (_Float16)a2[mt][r];
          }
        }
      }
  }
}

// ---- node layer 2 (MFMA): H2 (normal) -> Q3,P2 ----
__global__ __launch_bounds__(256) void node2_kernel(
    const unsigned* __restrict__ H2,
    const uint4* __restrict__ Wn3f, const uint4* __restrict__ Wc2f,
    _Float16* __restrict__ Q3h, _Float16* __restrict__ P2h)
{
  __shared__ __align__(16) _Float16 t_lds[64 * 72];
  int tid = threadIdx.x, lane = tid & 63, w = tid >> 6;
  int nbase = blockIdx.x * 64;
#pragma unroll
  for (int rep = 0; rep < 2; ++rep) {
    int uidx = rep * 1024 + tid * 4;
    int node = uidx >> 5, c = uidx & 31;
    int gn = nbase + node; if (gn > N_NODES - 1) gn = N_NODES - 1;
    uint4 tv = *(const uint4*)(H2 + (size_t)gn * 32 + c);
    *(uint4*)(t_lds + node * 72 + c * 2) = tv;
  }
  __syncthreads();
  int row16 = lane & 15, chunk = lane >> 4;
  int mat = w >> 1, nt = w & 1;
  const uint4* Wf = mat ? Wc2f : Wn3f;
  uint4 bf0 = Wf[(nt * 2 + 0) * 64 + lane];
  uint4 bf1 = Wf[(nt * 2 + 1) * 64 + lane];
  f32x4 a2[4];
#pragma unroll
  for (int mt = 0; mt < 4; ++mt) a2[mt] = (f32x4){0.f, 0.f, 0.f, 0.f};
#pragma unroll
  for (int mt = 0; mt < 4; ++mt) {
    const _Float16* ab = t_lds + (mt * 16 + row16) * 72 + chunk * 8;
    f16x8 A0 = *(const f16x8*)ab;
    f16x8 A1 = *(const f16x8*)(ab + 32);
    a2[mt] = MFMA16(A0, bf0, a2[mt]);
    a2[mt] = MFMA16(A1, bf1, a2[mt]);
  }
  _Float16* op = mat ? P2h : Q3h;
#pragma unroll
  for (int mt = 0; mt < 4; ++mt)
#pragma unroll
    for (int r = 0; r < 4; ++r) {
      int gn = nbase + mt * 16 + chunk * 4 + r;
      if (gn < N_NODES) op[(size_t)gn * 32 + nt * 16 + row16] = (_Float16)a2[mt][r];
    }
}

// ---- edge kernel: CSR-ordered edges, hoisted c1 loads, MFMA ----
__global__ __launch_bounds__(256) void edge_kernel(
    const uint2* __restrict__ ce, const int* __restrict__ did,
    const unsigned* __restrict__ P1_16, const unsigned* __restrict__ P2_16,
    const _Float16* __restrict__ P3_16, const uint4* __restrict__ Bfrag,
    const float* __restrict__ bc1, const float* __restrict__ bc2,
    const float* __restrict__ bc3, const float* __restrict__ bg1,
    const float* __restrict__ Wg2, const float* __restrict__ bg2,
    float* __restrict__ out)
{
  __shared__ __align__(16) _Float16 sbuf[4][32 * 104];
  __shared__ int eidx[4][64];
  __shared__ int eido[4][32];
  int lane = threadIdx.x & 63;
  int w = threadIdx.x >> 6;
  // XCD-bijective block swizzle: nwg=6250 = 8*781+2
  int b = blockIdx.x;
  int xcd = b & 7, idx = b >> 3;
  int swz = (xcd < 2 ? xcd * 782 : 2 * 782 + (xcd - 2) * 781) + idx;
  int ebase = swz * 128 + w * 32;
  _Float16* wb = &sbuf[w][0];

  int e32 = lane & 31;
  int myi;
  if (lane < 32) {
    uint2 cv2 = ce[ebase + e32];
    myi = (int)cv2.x;
    eido[w][e32] = (int)cv2.y;
  } else {
    myi = did[ebase + e32];
  }
  eidx[w][lane] = myi;

  f16x8 Bf[2][2];
#pragma unroll
  for (int ks = 0; ks < 2; ++ks)
#pragma unroll
    for (int nh = 0; nh < 2; ++nh)
      Bf[ks][nh] = __builtin_bit_cast(f16x8, Bfrag[(ks * 2 + nh) * 64 + lane]);

  {
    float p3v = (float)P3_16[myi];
    float pair = __shfl_xor(p3v, 32);
    if (lane < 32) wb[e32 * 104 + 96] = (_Float16)(p3v + pair);
  }
  // c1: 8 edges / iter x 4 iters, ALL loads hoisted before compute
  {
    int c = lane & 7, q = lane >> 3;
    uint4 ps[4], pd[4];
#pragma unroll
    for (int it = 0; it < 4; ++it) {
      int e = 8 * it + q;
      int s = eidx[w][e];
      int d = eidx[w][32 + e];
      ps[it] = *(const uint4*)(P1_16 + (size_t)s * 32 + 4 * c);
      pd[it] = *(const uint4*)(P1_16 + (size_t)d * 32 + 4 * c);
    }
    unsigned b10 = packh2(bc1[8 * c],     bc1[8 * c + 1]);
    unsigned b11 = packh2(bc1[8 * c + 2], bc1[8 * c + 3]);
    unsigned b12 = packh2(bc1[8 * c + 4], bc1[8 * c + 5]);
    unsigned b13 = packh2(bc1[8 * c + 6], bc1[8 * c + 7]);
#pragma unroll
    for (int it = 0; it < 4; ++it) {
      int e = 8 * it + q;
      h2 v0 = __builtin_bit_cast(h2, addpk(addpk(ps[it].x, pd[it].x), b10));
      h2 v1 = __builtin_bit_cast(h2, addpk(addpk(ps[it].y, pd[it].y), b11));
      h2 v2 = __builtin_bit_cast(h2, addpk(addpk(ps[it].z, pd[it].z), b12));
      h2 v3 = __builtin_bit_cast(h2, addpk(addpk(ps[it].w, pd[it].w), b13));
      uint4 o;
      o.x = packh2(sigf((float)v0.x), sigf((float)v0.y));
      o.y = packh2(sigf((float)v1.x), sigf((float)v1.y));
      o.z = packh2(sigf((float)v2.x), sigf((float)v2.y));
      o.w = packh2(sigf((float)v3.x), sigf((float)v3.y));
      *(uint4*)(wb + e * 104 + 8 * c) = o;
    }
  }
  // c2: 16 edges / iter, uint4 per lane
  {
    int c = lane & 3, q = lane >> 2;
    unsigned b20 = packh2(bc2[8 * c],     bc2[8 * c + 1]);
    unsigned b21 = packh2(bc2[8 * c + 2], bc2[8 * c + 3]);
    unsigned b22 = packh2(bc2[8 * c + 4], bc2[8 * c + 5]);
    unsigned b23 = packh2(bc2[8 * c + 6], bc2[8 * c + 7]);
#pragma unroll
    for (int it = 0; it < 2; ++it) {
      int e = 16 * it + q;
      int s = eidx[w][e];
      int d = eidx[w][32 + e];
      uint4 ps = *(const uint4*)(P2_16 + (size_t)s * 16 + 4 * c);
      uint4 pd = *(const uint4*)(P2_16 + (size_t)d * 16 + 4 * c);
      h2 v0 = __builtin_bit_cast(h2, addpk(addpk(ps.x, pd.x), b20));
      h2 v1 = __builtin_bit_cast(h2, addpk(addpk(ps.y, pd.y), b21));
      h2 v2 = __builtin_bit_cast(h2, addpk(addpk(ps.z, pd.z), b22));
      h2 v3 = __builtin_bit_cast(h2, addpk(addpk(ps.w, pd.w), b23));
      uint4 o;
      o.x = packh2(sigf((float)v0.x), sigf((float)v0.y));
      o.y = packh2(sigf((float)v1.x), sigf((float)v1.y));
      o.z = packh2(sigf((float)v2.x), sigf((float)v2.y));
      o.w = packh2(sigf((float)v3.x), sigf((float)v3.y));
      *(uint4*)(wb + e * 104 + 64 + 8 * c) = o;
    }
  }

  int row = lane & 15, chunk = lane >> 4;
  float bg1v0 = bg1[row], bg1v1 = bg1[16 + row];
  float wg2v0 = Wg2[row], wg2v1 = Wg2[16 + row];
  float bg2v = bg2[0], bc3v = bc3[0];
#pragma unroll
  for (int g = 0; g < 2; ++g) {
    const _Float16* abase = wb + (16 * g + row) * 104 + chunk * 8;
    f16x8 A0 = *(const f16x8*)abase;
    f16x8 A1 = *(const f16x8*)(abase + 32);
    f32x4 acc0 = {0.f, 0.f, 0.f, 0.f}, acc1 = {0.f, 0.f, 0.f, 0.f};
    acc0 = __builtin_amdgcn_mfma_f32_16x16x32_f16(A0, Bf[0][0], acc0, 0, 0, 0);
    acc1 = __builtin_amdgcn_mfma_f32_16x16x32_f16(A0, Bf[0][1], acc1, 0, 0, 0);
    acc0 = __builtin_amdgcn_mfma_f32_16x16x32_f16(A1, Bf[1][0], acc0, 0, 0, 0);
    acc1 = __builtin_amdgcn_mfma_f32_16x16x32_f16(A1, Bf[1][1], acc1, 0, 0, 0);
#pragma unroll
    for (int r = 0; r < 4; ++r) {
      int e = 16 * g + chunk * 4 + r;
      float c2a = (float)wb[e * 104 + 64 + row];
      float c2b = (float)wb[e * 104 + 80 + row];
      float v0 = sigf(acc0[r] + bg1v0 + c2a) * wg2v0;
      float v1 = sigf(acc1[r] + bg1v1 + c2b) * wg2v1;
      float part = v0 + v1;
      part += __shfl_xor(part, 1);
      part += __shfl_xor(part, 2);
      part += __shfl_xor(part, 4);
      part += __shfl_xor(part, 8);
      float c3v = (float)wb[e * 104 + 96];
      if (row == 0)
        out[eido[w][e]] = sigf(part + bg2v + sigf(c3v + bc3v));
    }
  }
}

extern "C" void kernel_launch(void* const* d_in, const int* in_sizes, int n_in,
                              void* d_out, int out_size, void* d_ws, size_t ws_size,
                              hipStream_t stream)
{
  const float* x   = (const float*)d_in[0];
  const int*   src = (const int*)d_in[1];
  const int*   dst = (const int*)d_in[2];
  const float* Wn1 = (const float*)d_in[3];
  const float* bn1 = (const float*)d_in[4];
  const float* Wc1 = (const float*)d_in[5];
  const float* bc1 = (const float*)d_in[6];
  const float* Wn2 = (const float*)d_in[7];
  const float* bn2 = (const float*)d_in[8];
  const float* Wc2 = (const float*)d_in[9];
  const float* bc2 = (const float*)d_in[10];
  const float* Wn3 = (const float*)d_in[11];
  const float* bn3 = (const float*)d_in[12];
  const float* Wc3 = (const float*)d_in[13];
  const float* bc3 = (const float*)d_in[14];
  const float* Wg1 = (const float*)d_in[15];
  const float* bg1 = (const float*)d_in[16];
  const float* Wg2 = (const float*)d_in[17];
  const float* bg2 = (const float*)d_in[18];
  float* out = (float*)d_out;

  char* base = (char*)d_ws;
  unsigned* TMP16 = (unsigned*)base; base += (size_t)N_NODES * 32 * 4;   // T16s / H2
  unsigned* X16s  = (unsigned*)base; base += (size_t)N_NODES * 32 * 4;   // split [2][N][16]
  unsigned* Q2s   = (unsigned*)base; base += (size_t)N_NODES * 32 * 4;   // split [2][N][16]
  unsigned* P1_16 = (unsigned*)base; base += (size_t)N_NODES * 32 * 4;
  unsigned* Q3_16 = (unsigned*)base; base += (size_t)N_NODES * 16 * 4;
  unsigned* P2_16 = (unsigned*)base; base += (size_t)N_NODES * 16 * 4;
  _Float16* P3_16 = (_Float16*)base; base += ((size_t)N_NODES * 2 + 15) / 16 * 16;
  int* rowptr = (int*)base;          base += (size_t)(N_NODES + 1) * 4;
  int* cursor = (int*)base;          base += (size_t)N_NODES * 4 + 12;
  uint2* ce   = (uint2*)base;        base += (size_t)N_EDGES * 8;
  int* did    = (int*)base;          base += (size_t)N_EDGES * 4;
  int* bsum   = (int*)base;          base += (size_t)NBLK_SCAN * 4 + 12;
  uint4* Wg1f = (uint4*)base;        base += 4 * 64 * 16;
  uint4* Wn1f = (uint4*)base;        base += 16 * 64 * 16;
  uint4* Wn2f = (uint4*)base;        base += 16 * 64 * 16;
  uint4* Wc1f = (uint4*)base;        base += 16 * 64 * 16;
  uint4* Wn3f = (uint4*)base;        base += 4 * 64 * 16;
  uint4* Wc2f = (uint4*)base;        base += 4 * 64 * 16;

  // prep (cvt + hist + frag-pack) and CSR build
  hipMemsetAsync(cursor, 0, (size_t)N_NODES * sizeof(int), stream);
  prep_kernel<<<CVT_B + HIST_B + 1, 256, 0, stream>>>(x, X16s, dst, cursor,
      Wn1, Wn2, Wc1, Wn3, Wc2, Wg1, Wn1f, Wn2f, Wc1f, Wn3f, Wc2f, Wg1f);
  scan1_kernel<<<NBLK_SCAN, 256, 0, stream>>>(cursor, bsum);
  scan3_kernel<<<NBLK_SCAN, 256, 0, stream>>>(cursor, bsum, rowptr, cursor, did);
  fill_kernel<<<HIST_B, 256, 0, stream>>>(src, dst, cursor, ce);

  // layer 1: T16s = x + agg(x) (split); node1 -> Q2s (split), P1
  gather1_kernel<<<G12_B, 256, 0, stream>>>(X16s, rowptr, (const int*)ce, TMP16);
  node1_kernel<<<NODE_B, 256, 0, stream>>>(TMP16, Wn1f, Wn2f, Wc1f, bn1,
      (_Float16*)Q2s, (_Float16*)P1_16);
  // layer 2: H2 = sig(Q2 + agg(Q2) + bn2) (normal); node2 -> Q3, P2
  gather2_kernel<<<G12_B, 256, 0, stream>>>(Q2s, rowptr, (const int*)ce, bn2, TMP16);
  node2_kernel<<<NODE_B, 256, 0, stream>>>(TMP16, Wn3f, Wc2f,
      (_Float16*)Q3_16, (_Float16*)P2_16);
  // layer 3 (gather + node3 fused) -> P3
  gather3_kernel<<<(N_NODES + 3) / 4, 256, 0, stream>>>(Q3_16, rowptr, (const int*)ce, bn3, Wc3, P3_16);
  // edge-level epilogue in CSR (dst-sorted) order
  edge_kernel<<<EDGE_B, 256, 0, stream>>>(ce, did, P1_16, P2_16, P3_16, Wg1f,
      bc1, bc2, bc3, bg1, Wg2, bg2, out);
}

// Round 12
// 178.866 us; speedup vs baseline: 1.4759x; 1.4759x over previous
//
#include <hip/hip_runtime.h>

#define N_NODES 50000
#define N_EDGES 800000
#define CVT_B 6250                          // N_NODES*32/256
#define NODE_B ((N_NODES + 63) / 64)        // 782
#define EDGE_B (N_EDGES / 128)              // 6250
#define NB 196                              // dst buckets (256 nodes each)
#define FILL_B 196                          // edge chunks of 4096
#define FILL_CHUNK 4096

typedef _Float16 h2 __attribute__((ext_vector_type(2)));
typedef _Float16 f16x8 __attribute__((ext_vector_type(8)));
typedef float f32x4 __attribute__((ext_vector_type(4)));

__device__ __forceinline__ float sigf(float v) {
  return __builtin_amdgcn_rcpf(1.0f + __expf(-v));
}
__device__ __forceinline__ unsigned packh2(float a, float b) {
  return __builtin_bit_cast(unsigned, __builtin_amdgcn_cvt_pkrtz(a, b));
}
__device__ __forceinline__ float2 unpackh2(unsigned u) {
  h2 p = __builtin_bit_cast(h2, u);
  return make_float2((float)p.x, (float)p.y);
}
__device__ __forceinline__ void acc8(float* a, uint4 v) {
  float2 p0 = unpackh2(v.x), p1 = unpackh2(v.y);
  float2 p2 = unpackh2(v.z), p3 = unpackh2(v.w);
  a[0] += p0.x; a[1] += p0.y; a[2] += p1.x; a[3] += p1.y;
  a[4] += p2.x; a[5] += p2.y; a[6] += p3.x; a[7] += p3.y;
}
__device__ __forceinline__ unsigned addpk(unsigned a, unsigned b) {
  h2 r = __builtin_bit_cast(h2, a) + __builtin_bit_cast(h2, b);
  return __builtin_bit_cast(unsigned, r);
}
#define MFMA16(A, B, C) __builtin_amdgcn_mfma_f32_16x16x32_f16(A, __builtin_bit_cast(f16x8, B), C, 0, 0, 0)

// ---- prep: x->f16 | weight matrices -> MFMA B-frag layout (no hist) ----
__global__ __launch_bounds__(256) void prep_kernel(
    const float* __restrict__ x, unsigned* __restrict__ x16,
    const float* __restrict__ Wn1, const float* __restrict__ Wn2,
    const float* __restrict__ Wc1, const float* __restrict__ Wn3,
    const float* __restrict__ Wc2, const float* __restrict__ Wg1,
    uint4* __restrict__ Wn1f, uint4* __restrict__ Wn2f, uint4* __restrict__ Wc1f,
    uint4* __restrict__ Wn3f, uint4* __restrict__ Wc2f, uint4* __restrict__ Wg1f)
{
  int b = blockIdx.x;
  if (b < CVT_B) {
    int i = b * 256 + threadIdx.x;
    float2 v = ((const float2*)x)[i];
    x16[i] = packh2(v.x, v.y);
  } else {
    int lane = threadIdx.x & 63, w = threadIdx.x >> 6;
    int n15 = lane & 15, chunk = lane >> 4;
    if (w == 0) {           // Wn1f: K=64, N=128 -> 8 nt x 2 ks
#pragma unroll
      for (int f = 0; f < 16; ++f) {
        int nt = f >> 1, ks = f & 1;
        int n = nt * 16 + n15;
        f16x8 vv;
#pragma unroll
        for (int i = 0; i < 8; ++i) vv[i] = (_Float16)Wn1[(ks * 32 + chunk * 8 + i) * 128 + n];
        Wn1f[f * 64 + lane] = __builtin_bit_cast(uint4, vv);
      }
    } else if (w == 1) {    // Wn2f: K=128, N=64 -> 4 nt x 4 ks
#pragma unroll
      for (int f = 0; f < 16; ++f) {
        int nt = f >> 2, ks = f & 3;
        int n = nt * 16 + n15;
        f16x8 vv;
#pragma unroll
        for (int i = 0; i < 8; ++i) vv[i] = (_Float16)Wn2[(ks * 32 + chunk * 8 + i) * 64 + n];
        Wn2f[f * 64 + lane] = __builtin_bit_cast(uint4, vv);
      }
    } else if (w == 2) {    // Wc1f: K=128, N=64 -> 4 nt x 4 ks
#pragma unroll
      for (int f = 0; f < 16; ++f) {
        int nt = f >> 2, ks = f & 3;
        int n = nt * 16 + n15;
        f16x8 vv;
#pragma unroll
        for (int i = 0; i < 8; ++i) vv[i] = (_Float16)Wc1[(ks * 32 + chunk * 8 + i) * 64 + n];
        Wc1f[f * 64 + lane] = __builtin_bit_cast(uint4, vv);
      }
    } else {                // Wn3f, Wc2f: K=64,N=32; Wg1f
#pragma unroll
      for (int f = 0; f < 4; ++f) {
        int nt = f >> 1, ks = f & 1;
        int n = nt * 16 + n15;
        f16x8 v3, vc;
#pragma unroll
        for (int i = 0; i < 8; ++i) {
          int k = ks * 32 + chunk * 8 + i;
          v3[i] = (_Float16)Wn3[k * 32 + n];
          vc[i] = (_Float16)Wc2[k * 32 + n];
        }
        Wn3f[f * 64 + lane] = __builtin_bit_cast(uint4, v3);
        Wc2f[f * 64 + lane] = __builtin_bit_cast(uint4, vc);
      }
#pragma unroll
      for (int ks = 0; ks < 2; ++ks)
#pragma unroll
        for (int nh = 0; nh < 2; ++nh) {
          f16x8 vv;
#pragma unroll
          for (int i = 0; i < 8; ++i)
            vv[i] = (_Float16)Wg1[(ks * 32 + chunk * 8 + i) * 32 + nh * 16 + n15];
          Wg1f[(ks * 2 + nh) * 64 + lane] = __builtin_bit_cast(uint4, vv);
        }
    }
  }
}

// ---- fill1: per-chunk histogram over NB buckets (dst>>8) ----
__global__ __launch_bounds__(256) void fill1_kernel(
    const int* __restrict__ dst, int* __restrict__ histM)
{
  __shared__ int hist[NB];
  int tid = threadIdx.x, bid = blockIdx.x;
  if (tid < NB) hist[tid] = 0;
  __syncthreads();
  int ebase = bid * FILL_CHUNK;
#pragma unroll
  for (int it = 0; it < FILL_CHUNK / 256; ++it) {
    int e = ebase + it * 256 + tid;
    if (e < N_EDGES) atomicAdd(&hist[dst[e] >> 8], 1);
  }
  __syncthreads();
  if (tid < NB) histM[bid * NB + tid] = hist[tid];
}

// ---- scanA: bucketBase + per-(chunk,bucket) offsets ----
__global__ __launch_bounds__(256) void scanA_kernel(
    const int* __restrict__ histM, int* __restrict__ colOff,
    int* __restrict__ bucketBase)
{
  int j = threadIdx.x, lane = j & 63, w = j >> 6;
  int total = 0;
  if (j < NB)
    for (int i = 0; i < FILL_B; ++i) total += histM[i * NB + j];
  // block exclusive scan of total
  int x = total;
#pragma unroll
  for (int off = 1; off < 64; off <<= 1) {
    int y = __shfl_up(x, off);
    if (lane >= off) x += y;
  }
  __shared__ int ws[4];
  if (lane == 63) ws[w] = x;
  __syncthreads();
  int woff = 0;
#pragma unroll
  for (int k = 0; k < 4; ++k) if (k < w) woff += ws[k];
  int excl = woff + x - total;
  if (j < NB) {
    bucketBase[j] = excl;
    int running = excl;
    for (int i = 0; i < FILL_B; ++i) {
      colOff[i * NB + j] = running;
      running += histM[i * NB + j];
    }
    if (j == NB - 1) bucketBase[NB] = running;   // == N_EDGES
  }
}

// ---- fill2: scatter edges into per-(chunk,bucket) contiguous slots ----
__global__ __launch_bounds__(256) void fill2_kernel(
    const int* __restrict__ src, const int* __restrict__ dst,
    const int* __restrict__ colOff, uint2* __restrict__ cem)
{
  __shared__ int cur[NB];
  int tid = threadIdx.x, bid = blockIdx.x;
  if (tid < NB) cur[tid] = colOff[bid * NB + tid];
  __syncthreads();
  int ebase = bid * FILL_CHUNK;
#pragma unroll
  for (int it = 0; it < FILL_CHUNK / 256; ++it) {
    int e = ebase + it * 256 + tid;
    if (e < N_EDGES) {
      int s = src[e], d = dst[e];
      int pos = atomicAdd(&cur[d >> 8], 1);
      cem[pos] = make_uint2((unsigned)s, ((unsigned)(d & 255) << 20) | (unsigned)e);
    }
  }
}

// ---- fill3: per-bucket counting sort by exact dst -> ce, rowptr, did ----
__global__ __launch_bounds__(256) void fill3_kernel(
    const uint2* __restrict__ cem, const int* __restrict__ bucketBase,
    uint2* __restrict__ ce, int* __restrict__ rowptr, int* __restrict__ did)
{
  __shared__ int cnt[256], curs[256], ws[4];
  int j = blockIdx.x, tid = threadIdx.x;
  int base = bucketBase[j], endb = bucketBase[j + 1];
  cnt[tid] = 0;
  __syncthreads();
  for (int k = base + tid; k < endb; k += 256)
    atomicAdd(&cnt[(cem[k].y >> 20) & 255], 1);
  __syncthreads();
  int v = cnt[tid];
  int lane = tid & 63, w = tid >> 6;
  int x = v;
#pragma unroll
  for (int off = 1; off < 64; off <<= 1) {
    int y = __shfl_up(x, off);
    if (lane >= off) x += y;
  }
  if (lane == 63) ws[w] = x;
  __syncthreads();
  int woff = 0;
#pragma unroll
  for (int k = 0; k < 4; ++k) if (k < w) woff += ws[k];
  int ex = woff + x - v;        // exclusive prefix within bucket
  curs[tid] = ex;
  int n = j * 256 + tid;
  if (n < N_NODES) {
    rowptr[n + 1] = base + ex + v;
    if (n == 0) rowptr[0] = 0;
    for (int k2 = 0; k2 < v; ++k2) did[base + ex + k2] = n;
  }
  __syncthreads();
  for (int k = base + tid; k < endb; k += 256) {
    uint2 r = cem[k];
    int dlow = (r.y >> 20) & 255;
    int pos = base + atomicAdd(&curs[dlow], 1);
    ce[pos] = make_uint2(r.x, r.y & 0xFFFFFu);
  }
}

// ---- gather1: T16[n] = x16[n] + sum x16[src]; uint4 rows, 8 edges/iter ----
__global__ __launch_bounds__(256) void gather1_kernel(
    const unsigned* __restrict__ X16, const int* __restrict__ rowptr,
    const int* __restrict__ ce2, unsigned* __restrict__ T16)
{
  int w = threadIdx.x >> 6, lane = threadIdx.x & 63;
  int n = blockIdx.x * 4 + w;
  if (n >= N_NODES) return;
  int beg = rowptr[n], end = rowptr[n + 1];
  int q = lane >> 3, c = lane & 7;
  const uint4* feat4 = (const uint4*)X16;
  float a[8] = {0.f, 0.f, 0.f, 0.f, 0.f, 0.f, 0.f, 0.f};
  for (int k0 = beg; k0 < end; k0 += 64) {
    int kk = k0 + lane;
    int cv = (kk < end) ? ce2[2 * kk] : 0;
    int m = end - k0; if (m > 64) m = 64;
    int e = 0;
#pragma unroll 2
    for (; e + 7 < m; e += 8) {
      int se = __shfl(cv, e + q);
      acc8(a, feat4[(size_t)se * 8 + c]);
    }
    int r = m - e;
    if (r) {
      int idx = e + q; if (idx >= m) idx = m - 1;
      int se = __shfl(cv, idx);
      uint4 v = feat4[(size_t)se * 8 + c];
      if (q < r) acc8(a, v);
    }
  }
#pragma unroll
  for (int j = 0; j < 8; ++j) {
    a[j] += __shfl_xor(a[j], 32);
    a[j] += __shfl_xor(a[j], 16);
    a[j] += __shfl_xor(a[j], 8);
  }
  if (q == 0) {
    uint4 xv = ((const uint4*)X16)[(size_t)n * 8 + c];
    float2 x0 = unpackh2(xv.x), x1 = unpackh2(xv.y);
    float2 x2 = unpackh2(xv.z), x3 = unpackh2(xv.w);
    uint4 o;
    o.x = packh2(a[0] + x0.x, a[1] + x0.y);
    o.y = packh2(a[2] + x1.x, a[3] + x1.y);
    o.z = packh2(a[4] + x2.x, a[5] + x2.y);
    o.w = packh2(a[6] + x3.x, a[7] + x3.y);
    ((uint4*)T16)[(size_t)n * 8 + c] = o;
  }
}

// ---- gather2: H2[n] = sig(Q2[n] + sum Q2[src] + bn2); 8 edges/iter ----
__global__ __launch_bounds__(256) void gather2_kernel(
    const unsigned* __restrict__ Q2u, const int* __restrict__ rowptr,
    const int* __restrict__ ce2, const float* __restrict__ bn2,
    unsigned* __restrict__ H2)
{
  int w = threadIdx.x >> 6, lane = threadIdx.x & 63;
  int n = blockIdx.x * 4 + w;
  if (n >= N_NODES) return;
  int beg = rowptr[n], end = rowptr[n + 1];
  int q = lane >> 3, c = lane & 7;
  const uint4* feat4 = (const uint4*)Q2u;
  float a[8] = {0.f, 0.f, 0.f, 0.f, 0.f, 0.f, 0.f, 0.f};
  for (int k0 = beg; k0 < end; k0 += 64) {
    int kk = k0 + lane;
    int cv = (kk < end) ? ce2[2 * kk] : 0;
    int m = end - k0; if (m > 64) m = 64;
    int e = 0;
#pragma unroll 2
    for (; e + 7 < m; e += 8) {
      int se = __shfl(cv, e + q);
      acc8(a, feat4[(size_t)se * 8 + c]);
    }
    int r = m - e;
    if (r) {
      int idx = e + q; if (idx >= m) idx = m - 1;
      int se = __shfl(cv, idx);
      uint4 v = feat4[(size_t)se * 8 + c];
      if (q < r) acc8(a, v);
    }
  }
#pragma unroll
  for (int j = 0; j < 8; ++j) {
    a[j] += __shfl_xor(a[j], 32);
    a[j] += __shfl_xor(a[j], 16);
    a[j] += __shfl_xor(a[j], 8);
  }
  if (q == 0) {
    uint4 qv = ((const uint4*)Q2u)[(size_t)n * 8 + c];
    float4 bnA = ((const float4*)bn2)[2 * c];
    float4 bnB = ((const float4*)bn2)[2 * c + 1];
    float2 q0 = unpackh2(qv.x), q1 = unpackh2(qv.y);
    float2 q2 = unpackh2(qv.z), q3 = unpackh2(qv.w);
    uint4 o;
    o.x = packh2(sigf(a[0] + q0.x + bnA.x), sigf(a[1] + q0.y + bnA.y));
    o.y = packh2(sigf(a[2] + q1.x + bnA.z), sigf(a[3] + q1.y + bnA.w));
    o.z = packh2(sigf(a[4] + q2.x + bnB.x), sigf(a[5] + q2.y + bnB.y));
    o.w = packh2(sigf(a[6] + q3.x + bnB.z), sigf(a[7] + q3.y + bnB.w));
    ((uint4*)H2)[(size_t)n * 8 + c] = o;
  }
}

// ---- gather3 + node3 fused: 16 edges/iter ----
__global__ __launch_bounds__(256) void gather3_kernel(
    const unsigned* __restrict__ Q3u, const int* __restrict__ rowptr,
    const int* __restrict__ ce2, const float* __restrict__ bn3,
    const float* __restrict__ Wc3, _Float16* __restrict__ P3h)
{
  int w = threadIdx.x >> 6, lane = threadIdx.x & 63;
  int n = blockIdx.x * 4 + w;
  if (n >= N_NODES) return;
  int beg = rowptr[n], end = rowptr[n + 1];
  int q = lane >> 2, c = lane & 3;
  const uint4* feat4 = (const uint4*)Q3u;
  float a[8] = {0.f, 0.f, 0.f, 0.f, 0.f, 0.f, 0.f, 0.f};
  for (int k0 = beg; k0 < end; k0 += 64) {
    int kk = k0 + lane;
    int cv = (kk < end) ? ce2[2 * kk] : 0;
    int m = end - k0; if (m > 64) m = 64;
    int e = 0;
#pragma unroll 2
    for (; e + 15 < m; e += 16) {
      int se = __shfl(cv, e + q);
      acc8(a, feat4[(size_t)se * 4 + c]);
    }
    int r = m - e;
    if (r) {
      int idx = e + q; if (idx >= m) idx = m - 1;
      int se = __shfl(cv, idx);
      uint4 v = feat4[(size_t)se * 4 + c];
      if (q < r) acc8(a, v);
    }
  }
#pragma unroll
  for (int j = 0; j < 8; ++j) {
    a[j] += __shfl_xor(a[j], 32);
    a[j] += __shfl_xor(a[j], 16);
    a[j] += __shfl_xor(a[j], 8);
    a[j] += __shfl_xor(a[j], 4);
  }
  if (q == 0) {
    uint4 qv = feat4[(size_t)n * 4 + c];
    float4 bnA = ((const float4*)bn3)[2 * c], bnB = ((const float4*)bn3)[2 * c + 1];
    float4 wcA = ((const float4*)Wc3)[2 * c], wcB = ((const float4*)Wc3)[2 * c + 1];
    float2 q0 = unpackh2(qv.x), q1 = unpackh2(qv.y);
    float2 q2 = unpackh2(qv.z), q3 = unpackh2(qv.w);
    float p = sigf(a[0] + q0.x + bnA.x) * wcA.x + sigf(a[1] + q0.y + bnA.y) * wcA.y
            + sigf(a[2] + q1.x + bnA.z) * wcA.z + sigf(a[3] + q1.y + bnA.w) * wcA.w
            + sigf(a[4] + q2.x + bnB.x) * wcB.x + sigf(a[5] + q2.y + bnB.y) * wcB.y
            + sigf(a[6] + q3.x + bnB.z) * wcB.z + sigf(a[7] + q3.y + bnB.w) * wcB.w;
    p += __shfl_xor(p, 1); p += __shfl_xor(p, 2);
    if (c == 0) P3h[n] = (_Float16)p;
  }
}

// ---- node layer 1 (MFMA) ----
__global__ __launch_bounds__(256) void node1_kernel(
    const unsigned* __restrict__ T16,
    const uint4* __restrict__ Wn1f, const uint4* __restrict__ Wn2f,
    const uint4* __restrict__ Wc1f, const float* __restrict__ bn1,
    _Float16* __restrict__ Q2h, _Float16* __restrict__ P1h)
{
  __shared__ __align__(16) _Float16 t_lds[64 * 72];
  __shared__ __align__(16) _Float16 h1_lds[64 * 136];
  int tid = threadIdx.x;
  int lane = tid & 63, w = tid >> 6;
  int nbase = blockIdx.x * 64;

#pragma unroll
  for (int rep = 0; rep < 2; ++rep) {
    int uidx = rep * 1024 + tid * 4;
    int node = uidx >> 5, c = uidx & 31;
    int gn = nbase + node; if (gn > N_NODES - 1) gn = N_NODES - 1;
    uint4 tv = *(const uint4*)(T16 + (size_t)gn * 32 + c);
    *(uint4*)(t_lds + node * 72 + c * 2) = tv;
  }
  __syncthreads();

  int row16 = lane & 15, chunk = lane >> 4;
  uint4 b1[2][2];
#pragma unroll
  for (int ntl = 0; ntl < 2; ++ntl)
#pragma unroll
    for (int ks = 0; ks < 2; ++ks)
      b1[ntl][ks] = Wn1f[((2 * w + ntl) * 2 + ks) * 64 + lane];

  f32x4 acc[4][2];
#pragma unroll
  for (int mt = 0; mt < 4; ++mt)
#pragma unroll
    for (int ntl = 0; ntl < 2; ++ntl) acc[mt][ntl] = (f32x4){0.f, 0.f, 0.f, 0.f};
#pragma unroll
  for (int mt = 0; mt < 4; ++mt) {
    const _Float16* ab = t_lds + (mt * 16 + row16) * 72 + chunk * 8;
    f16x8 A0 = *(const f16x8*)ab;
    f16x8 A1 = *(const f16x8*)(ab + 32);
#pragma unroll
    for (int ntl = 0; ntl < 2; ++ntl) {
      acc[mt][ntl] = MFMA16(A0, b1[ntl][0], acc[mt][ntl]);
      acc[mt][ntl] = MFMA16(A1, b1[ntl][1], acc[mt][ntl]);
    }
  }
  float bnv0 = bn1[w * 32 + row16], bnv1 = bn1[w * 32 + 16 + row16];
#pragma unroll
  for (int mt = 0; mt < 4; ++mt)
#pragma unroll
    for (int r = 0; r < 4; ++r) {
      int rowl = mt * 16 + chunk * 4 + r;
      h1_lds[rowl * 136 + w * 32 + row16]      = (_Float16)sigf(acc[mt][0][r] + bnv0);
      h1_lds[rowl * 136 + w * 32 + 16 + row16] = (_Float16)sigf(acc[mt][1][r] + bnv1);
    }
  __syncthreads();

#pragma unroll
  for (int job = 0; job < 2; ++job) {
    const uint4* Wf = job ? Wc1f : Wn2f;
    uint4 bf[4];
#pragma unroll
    for (int ks = 0; ks < 4; ++ks) bf[ks] = Wf[(w * 4 + ks) * 64 + lane];
    f32x4 a2[4];
#pragma unroll
    for (int mt = 0; mt < 4; ++mt) a2[mt] = (f32x4){0.f, 0.f, 0.f, 0.f};
#pragma unroll
    for (int mt = 0; mt < 4; ++mt) {
      const _Float16* hb = h1_lds + (mt * 16 + row16) * 136 + chunk * 8;
#pragma unroll
      for (int ks = 0; ks < 4; ++ks) {
        f16x8 A = *(const f16x8*)(hb + ks * 32);
        a2[mt] = MFMA16(A, bf[ks], a2[mt]);
      }
    }
    _Float16* op = job ? P1h : Q2h;
#pragma unroll
    for (int mt = 0; mt < 4; ++mt)
#pragma unroll
      for (int r = 0; r < 4; ++r) {
        int gn = nbase + mt * 16 + chunk * 4 + r;
        if (gn < N_NODES) op[(size_t)gn * 64 + w * 16 + row16] = (_Float16)a2[mt][r];
      }
  }
}

// ---- node layer 2 (MFMA) ----
__global__ __launch_bounds__(256) void node2_kernel(
    const unsigned* __restrict__ H2,
    const uint4* __restrict__ Wn3f, const uint4* __restrict__ Wc2f,
    _Float16* __restrict__ Q3h, _Float16* __restrict__ P2h)
{
  __shared__ __align__(16) _Float16 t_lds[64 * 72];
  int tid = threadIdx.x, lane = tid & 63, w = tid >> 6;
  int nbase = blockIdx.x * 64;
#pragma unroll
  for (int rep = 0; rep < 2; ++rep) {
    int uidx = rep * 1024 + tid * 4;
    int node = uidx >> 5, c = uidx & 31;
    int gn = nbase + node; if (gn > N_NODES - 1) gn = N_NODES - 1;
    uint4 tv = *(const uint4*)(H2 + (size_t)gn * 32 + c);
    *(uint4*)(t_lds + node * 72 + c * 2) = tv;
  }
  __syncthreads();
  int row16 = lane & 15, chunk = lane >> 4;
  int mat = w >> 1, nt = w & 1;
  const uint4* Wf = mat ? Wc2f : Wn3f;
  uint4 bf0 = Wf[(nt * 2 + 0) * 64 + lane];
  uint4 bf1 = Wf[(nt * 2 + 1) * 64 + lane];
  f32x4 a2[4];
#pragma unroll
  for (int mt = 0; mt < 4; ++mt) a2[mt] = (f32x4){0.f, 0.f, 0.f, 0.f};
#pragma unroll
  for (int mt = 0; mt < 4; ++mt) {
    const _Float16* ab = t_lds + (mt * 16 + row16) * 72 + chunk * 8;
    f16x8 A0 = *(const f16x8*)ab;
    f16x8 A1 = *(const f16x8*)(ab + 32);
    a2[mt] = MFMA16(A0, bf0, a2[mt]);
    a2[mt] = MFMA16(A1, bf1, a2[mt]);
  }
  _Float16* op = mat ? P2h : Q3h;
#pragma unroll
  for (int mt = 0; mt < 4; ++mt)
#pragma unroll
    for (int r = 0; r < 4; ++r) {
      int gn = nbase + mt * 16 + chunk * 4 + r;
      if (gn < N_NODES) op[(size_t)gn * 32 + nt * 16 + row16] = (_Float16)a2[mt][r];
    }
}

// ---- edge kernel: CSR-ordered edges, uint4 staging, MFMA ----
__global__ __launch_bounds__(256) void edge_kernel(
    const uint2* __restrict__ ce, const int* __restrict__ did,
    const unsigned* __restrict__ P1_16, const unsigned* __restrict__ P2_16,
    const _Float16* __restrict__ P3_16, const uint4* __restrict__ Bfrag,
    const float* __restrict__ bc1, const float* __restrict__ bc2,
    const float* __restrict__ bc3, const float* __restrict__ bg1,
    const float* __restrict__ Wg2, const float* __restrict__ bg2,
    float* __restrict__ out)
{
  __shared__ __align__(16) _Float16 sbuf[4][32 * 104];
  __shared__ int eidx[4][64];
  __shared__ int eido[4][32];
  int lane = threadIdx.x & 63;
  int w = threadIdx.x >> 6;
  // XCD-bijective block swizzle: nwg=6250 = 8*781+2
  int b = blockIdx.x;
  int xcd = b & 7, idx = b >> 3;
  int swz = (xcd < 2 ? xcd * 782 : 2 * 782 + (xcd - 2) * 781) + idx;
  int ebase = swz * 128 + w * 32;
  _Float16* wb = &sbuf[w][0];

  int e32 = lane & 31;
  int myi;
  if (lane < 32) {
    uint2 cv2 = ce[ebase + e32];
    myi = (int)cv2.x;
    eido[w][e32] = (int)cv2.y;
  } else {
    myi = did[ebase + e32];
  }
  eidx[w][lane] = myi;

  f16x8 Bf[2][2];
#pragma unroll
  for (int ks = 0; ks < 2; ++ks)
#pragma unroll
    for (int nh = 0; nh < 2; ++nh)
      Bf[ks][nh] = __builtin_bit_cast(f16x8, Bfrag[(ks * 2 + nh) * 64 + lane]);

  {
    float p3v = (float)P3_16[myi];
    float pair = __shfl_xor(p3v, 32);
    if (lane < 32) wb[e32 * 104 + 96] = (_Float16)(p3v + pair);
  }
  // c1: 8 edges / iter, uint4 (8 f16) per lane
  {
    int c = lane & 7, q = lane >> 3;
    unsigned b10 = packh2(bc1[8 * c],     bc1[8 * c + 1]);
    unsigned b11 = packh2(bc1[8 * c + 2], bc1[8 * c + 3]);
    unsigned b12 = packh2(bc1[8 * c + 4], bc1[8 * c + 5]);
    unsigned b13 = packh2(bc1[8 * c + 6], bc1[8 * c + 7]);
#pragma unroll
    for (int it = 0; it < 4; ++it) {
      int e = 8 * it + q;
      int s = eidx[w][e];
      int d = eidx[w][32 + e];
      uint4 ps = *(const uint4*)(P1_16 + (size_t)s * 32 + 4 * c);
      uint4 pd = *(const uint4*)(P1_16 + (size_t)d * 32 + 4 * c);
      h2 v0 = __builtin_bit_cast(h2, addpk(addpk(ps.x, pd.x), b10));
      h2 v1 = __builtin_bit_cast(h2, addpk(addpk(ps.y, pd.y), b11));
      h2 v2 = __builtin_bit_cast(h2, addpk(addpk(ps.z, pd.z), b12));
      h2 v3 = __builtin_bit_cast(h2, addpk(addpk(ps.w, pd.w), b13));
      uint4 o;
      o.x = packh2(sigf((float)v0.x), sigf((float)v0.y));
      o.y = packh2(sigf((float)v1.x), sigf((float)v1.y));
      o.z = packh2(sigf((float)v2.x), sigf((float)v2.y));
      o.w = packh2(sigf((float)v3.x), sigf((float)v3.y));
      *(uint4*)(wb + e * 104 + 8 * c) = o;
    }
  }
  // c2: 16 edges / iter, uint4 per lane
  {
    int c = lane & 3, q = lane >> 2;
    unsigned b20 = packh2(bc2[8 * c],     bc2[8 * c + 1]);
    unsigned b21 = packh2(bc2[8 * c + 2], bc2[8 * c + 3]);
    unsigned b22 = packh2(bc2[8 * c + 4], bc2[8 * c + 5]);
    unsigned b23 = packh2(bc2[8 * c + 6], bc2[8 * c + 7]);
#pragma unroll
    for (int it = 0; it < 2; ++it) {
      int e = 16 * it + q;
      int s = eidx[w][e];
      int d = eidx[w][32 + e];
      uint4 ps = *(const uint4*)(P2_16 + (size_t)s * 16 + 4 * c);
      uint4 pd = *(const uint4*)(P2_16 + (size_t)d * 16 + 4 * c);
      h2 v0 = __builtin_bit_cast(h2, addpk(addpk(ps.x, pd.x), b20));
      h2 v1 = __builtin_bit_cast(h2, addpk(addpk(ps.y, pd.y), b21));
      h2 v2 = __builtin_bit_cast(h2, addpk(addpk(ps.z, pd.z), b22));
      h2 v3 = __builtin_bit_cast(h2, addpk(addpk(ps.w, pd.w), b23));
      uint4 o;
      o.x = packh2(sigf((float)v0.x), sigf((float)v0.y));
      o.y = packh2(sigf((float)v1.x), sigf((float)v1.y));
      o.z = packh2(sigf((float)v2.x), sigf((float)v2.y));
      o.w = packh2(sigf((float)v3.x), sigf((float)v3.y));
      *(uint4*)(wb + e * 104 + 64 + 8 * c) = o;
    }
  }

  int row = lane & 15, chunk = lane >> 4;
  float bg1v0 = bg1[row], bg1v1 = bg1[16 + row];
  float wg2v0 = Wg2[row], wg2v1 = Wg2[16 + row];
  float bg2v = bg2[0], bc3v = bc3[0];
#pragma unroll
  for (int g = 0; g < 2; ++g) {
    const _Float16* abase = wb + (16 * g + row) * 104 + chunk * 8;
    f16x8 A0 = *(const f16x8*)abase;
    f16x8 A1 = *(const f16x8*)(abase + 32);
    f32x4 acc0 = {0.f, 0.f, 0.f, 0.f}, acc1 = {0.f, 0.f, 0.f, 0.f};
    acc0 = __builtin_amdgcn_mfma_f32_16x16x32_f16(A0, Bf[0][0], acc0, 0, 0, 0);
    acc1 = __builtin_amdgcn_mfma_f32_16x16x32_f16(A0, Bf[0][1], acc1, 0, 0, 0);
    acc0 = __builtin_amdgcn_mfma_f32_16x16x32_f16(A1, Bf[1][0], acc0, 0, 0, 0);
    acc1 = __builtin_amdgcn_mfma_f32_16x16x32_f16(A1, Bf[1][1], acc1, 0, 0, 0);
#pragma unroll
    for (int r = 0; r < 4; ++r) {
      int e = 16 * g + chunk * 4 + r;
      float c2a = (float)wb[e * 104 + 64 + row];
      float c2b = (float)wb[e * 104 + 80 + row];
      float v0 = sigf(acc0[r] + bg1v0 + c2a) * wg2v0;
      float v1 = sigf(acc1[r] + bg1v1 + c2b) * wg2v1;
      float part = v0 + v1;
      part += __shfl_xor(part, 1);
      part += __shfl_xor(part, 2);
      part += __shfl_xor(part, 4);
      part += __shfl_xor(part, 8);
      float c3v = (float)wb[e * 104 + 96];
      if (row == 0)
        out[eido[w][e]] = sigf(part + bg2v + sigf(c3v + bc3v));
    }
  }
}

extern "C" void kernel_launch(void* const* d_in, const int* in_sizes, int n_in,
                              void* d_out, int out_size, void* d_ws, size_t ws_size,
                              hipStream_t stream)
{
  const float* x   = (const float*)d_in[0];
  const int*   src = (const int*)d_in[1];
  const int*   dst = (const int*)d_in[2];
  const float* Wn1 = (const float*)d_in[3];
  const float* bn1 = (const float*)d_in[4];
  const float* Wc1 = (const float*)d_in[5];
  const float* bc1 = (const float*)d_in[6];
  const float* Wn2 = (const float*)d_in[7];
  const float* bn2 = (const float*)d_in[8];
  const float* Wc2 = (const float*)d_in[9];
  const float* bc2 = (const float*)d_in[10];
  const float* Wn3 = (const float*)d_in[11];
  const float* bn3 = (const float*)d_in[12];
  const float* Wc3 = (const float*)d_in[13];
  const float* bc3 = (const float*)d_in[14];
  const float* Wg1 = (const float*)d_in[15];
  const float* bg1 = (const float*)d_in[16];
  const float* Wg2 = (const float*)d_in[17];
  const float* bg2 = (const float*)d_in[18];
  float* out = (float*)d_out;

  char* base = (char*)d_ws;
  unsigned* TMP16 = (unsigned*)base; base += (size_t)N_NODES * 32 * 4;   // T16 / H2
  unsigned* X16   = (unsigned*)base; base += (size_t)N_NODES * 32 * 4;
  unsigned* Q2_16 = (unsigned*)base; base += (size_t)N_NODES * 32 * 4;
  unsigned* P1_16 = (unsigned*)base; base += (size_t)N_NODES * 32 * 4;
  unsigned* Q3_16 = (unsigned*)base; base += (size_t)N_NODES * 16 * 4;
  unsigned* P2_16 = (unsigned*)base; base += (size_t)N_NODES * 16 * 4;
  _Float16* P3_16 = (_Float16*)base; base += ((size_t)N_NODES * 2 + 15) / 16 * 16;
  int* rowptr = (int*)base;          base += (size_t)(N_NODES + 1) * 4 + 12;
  uint2* ce   = (uint2*)base;        base += (size_t)N_EDGES * 8;
  uint2* cem  = (uint2*)base;        base += (size_t)N_EDGES * 8;
  int* did    = (int*)base;          base += (size_t)N_EDGES * 4;
  int* histM  = (int*)base;          base += (size_t)FILL_B * NB * 4;
  int* colOff = (int*)base;          base += (size_t)FILL_B * NB * 4;
  int* bucketBase = (int*)base;      base += (size_t)(NB + 1) * 4 + 12;
  uint4* Wg1f = (uint4*)base;        base += 4 * 64 * 16;
  uint4* Wn1f = (uint4*)base;        base += 16 * 64 * 16;
  uint4* Wn2f = (uint4*)base;        base += 16 * 64 * 16;
  uint4* Wc1f = (uint4*)base;        base += 16 * 64 * 16;
  uint4* Wn3f = (uint4*)base;        base += 4 * 64 * 16;
  uint4* Wc2f = (uint4*)base;        base += 4 * 64 * 16;

  // prep (cvt + frag-pack) and radix CSR build
  prep_kernel<<<CVT_B + 1, 256, 0, stream>>>(x, X16,
      Wn1, Wn2, Wc1, Wn3, Wc2, Wg1, Wn1f, Wn2f, Wc1f, Wn3f, Wc2f, Wg1f);
  fill1_kernel<<<FILL_B, 256, 0, stream>>>(dst, histM);
  scanA_kernel<<<1, 256, 0, stream>>>(histM, colOff, bucketBase);
  fill2_kernel<<<FILL_B, 256, 0, stream>>>(src, dst, colOff, cem);
  fill3_kernel<<<NB, 256, 0, stream>>>(cem, bucketBase, ce, rowptr, did);

  // layer 1: T16 = x + agg(x); node1 -> Q2, P1
  gather1_kernel<<<(N_NODES + 3) / 4, 256, 0, stream>>>(X16, rowptr, (const int*)ce, TMP16);
  node1_kernel<<<NODE_B, 256, 0, stream>>>(TMP16, Wn1f, Wn2f, Wc1f, bn1,
      (_Float16*)Q2_16, (_Float16*)P1_16);
  // layer 2: H2 = sig(Q2 + agg(Q2) + bn2); node2 -> Q3, P2
  gather2_kernel<<<(N_NODES + 3) / 4, 256, 0, stream>>>(Q2_16, rowptr, (const int*)ce, bn2, TMP16);
  node2_kernel<<<NODE_B, 256, 0, stream>>>(TMP16, Wn3f, Wc2f,
      (_Float16*)Q3_16, (_Float16*)P2_16);
  // layer 3 (gather + node3 fused) -> P3
  gather3_kernel<<<(N_NODES + 3) / 4, 256, 0, stream>>>(Q3_16, rowptr, (const int*)ce, bn3, Wc3, P3_16);
  // edge-level epilogue in CSR (dst-sorted) order
  edge_kernel<<<EDGE_B, 256, 0, stream>>>(ce, did, P1_16, P2_16, P3_16, Wg1f,
      bc1, bc2, bc3, bg1, Wg2, bg2, out);
}

// Round 13
// 178.026 us; speedup vs baseline: 1.4829x; 1.0047x over previous
//
#include <hip/hip_runtime.h>

#define N_NODES 50000
#define N_EDGES 800000
#define CVT_B 6250                          // N_NODES*32/256
#define NODE_B ((N_NODES + 63) / 64)        // 782
#define EDGE_B (N_EDGES / 128)              // 6250
#define NB 196                              // dst buckets (256 nodes each)
#define FILL_B 196                          // edge chunks of 4096
#define FILL_CHUNK 4096

typedef _Float16 h2 __attribute__((ext_vector_type(2)));
typedef _Float16 f16x8 __attribute__((ext_vector_type(8)));
typedef float f32x4 __attribute__((ext_vector_type(4)));

__device__ __forceinline__ float sigf(float v) {
  return __builtin_amdgcn_rcpf(1.0f + __expf(-v));
}
__device__ __forceinline__ unsigned packh2(float a, float b) {
  return __builtin_bit_cast(unsigned, __builtin_amdgcn_cvt_pkrtz(a, b));
}
__device__ __forceinline__ float2 unpackh2(unsigned u) {
  h2 p = __builtin_bit_cast(h2, u);
  return make_float2((float)p.x, (float)p.y);
}
__device__ __forceinline__ void acc8(float* a, uint4 v) {
  float2 p0 = unpackh2(v.x), p1 = unpackh2(v.y);
  float2 p2 = unpackh2(v.z), p3 = unpackh2(v.w);
  a[0] += p0.x; a[1] += p0.y; a[2] += p1.x; a[3] += p1.y;
  a[4] += p2.x; a[5] += p2.y; a[6] += p3.x; a[7] += p3.y;
}
__device__ __forceinline__ unsigned addpk(unsigned a, unsigned b) {
  h2 r = __builtin_bit_cast(h2, a) + __builtin_bit_cast(h2, b);
  return __builtin_bit_cast(unsigned, r);
}
#define MFMA16(A, B, C) __builtin_amdgcn_mfma_f32_16x16x32_f16(A, __builtin_bit_cast(f16x8, B), C, 0, 0, 0)

// ---- prep: x->f16 | per-chunk dst histogram | weights -> MFMA B-frag ----
__global__ __launch_bounds__(256) void prep_kernel(
    const float* __restrict__ x, unsigned* __restrict__ x16,
    const int* __restrict__ dst, int* __restrict__ histM,
    const float* __restrict__ Wn1, const float* __restrict__ Wn2,
    const float* __restrict__ Wc1, const float* __restrict__ Wn3,
    const float* __restrict__ Wc2, const float* __restrict__ Wg1,
    uint4* __restrict__ Wn1f, uint4* __restrict__ Wn2f, uint4* __restrict__ Wc1f,
    uint4* __restrict__ Wn3f, uint4* __restrict__ Wc2f, uint4* __restrict__ Wg1f)
{
  int b = blockIdx.x;
  if (b < CVT_B) {
    int i = b * 256 + threadIdx.x;
    float2 v = ((const float2*)x)[i];
    x16[i] = packh2(v.x, v.y);
  } else if (b < CVT_B + FILL_B) {
    // fill1: per-chunk histogram over NB buckets (dst>>8)
    __shared__ int hist[NB];
    int tid = threadIdx.x, bid = b - CVT_B;
    if (tid < NB) hist[tid] = 0;
    __syncthreads();
    int ebase = bid * FILL_CHUNK;
#pragma unroll
    for (int it = 0; it < FILL_CHUNK / 256; ++it) {
      int e = ebase + it * 256 + tid;
      if (e < N_EDGES) atomicAdd(&hist[dst[e] >> 8], 1);
    }
    __syncthreads();
    if (tid < NB) histM[bid * NB + tid] = hist[tid];
  } else {
    int lane = threadIdx.x & 63, w = threadIdx.x >> 6;
    int n15 = lane & 15, chunk = lane >> 4;
    if (w == 0) {           // Wn1f: K=64, N=128 -> 8 nt x 2 ks
#pragma unroll
      for (int f = 0; f < 16; ++f) {
        int nt = f >> 1, ks = f & 1;
        int n = nt * 16 + n15;
        f16x8 vv;
#pragma unroll
        for (int i = 0; i < 8; ++i) vv[i] = (_Float16)Wn1[(ks * 32 + chunk * 8 + i) * 128 + n];
        Wn1f[f * 64 + lane] = __builtin_bit_cast(uint4, vv);
      }
    } else if (w == 1) {    // Wn2f: K=128, N=64 -> 4 nt x 4 ks
#pragma unroll
      for (int f = 0; f < 16; ++f) {
        int nt = f >> 2, ks = f & 3;
        int n = nt * 16 + n15;
        f16x8 vv;
#pragma unroll
        for (int i = 0; i < 8; ++i) vv[i] = (_Float16)Wn2[(ks * 32 + chunk * 8 + i) * 64 + n];
        Wn2f[f * 64 + lane] = __builtin_bit_cast(uint4, vv);
      }
    } else if (w == 2) {    // Wc1f: K=128, N=64 -> 4 nt x 4 ks
#pragma unroll
      for (int f = 0; f < 16; ++f) {
        int nt = f >> 2, ks = f & 3;
        int n = nt * 16 + n15;
        f16x8 vv;
#pragma unroll
        for (int i = 0; i < 8; ++i) vv[i] = (_Float16)Wc1[(ks * 32 + chunk * 8 + i) * 64 + n];
        Wc1f[f * 64 + lane] = __builtin_bit_cast(uint4, vv);
      }
    } else {                // Wn3f, Wc2f: K=64,N=32; Wg1f
#pragma unroll
      for (int f = 0; f < 4; ++f) {
        int nt = f >> 1, ks = f & 1;
        int n = nt * 16 + n15;
        f16x8 v3, vc;
#pragma unroll
        for (int i = 0; i < 8; ++i) {
          int k = ks * 32 + chunk * 8 + i;
          v3[i] = (_Float16)Wn3[k * 32 + n];
          vc[i] = (_Float16)Wc2[k * 32 + n];
        }
        Wn3f[f * 64 + lane] = __builtin_bit_cast(uint4, v3);
        Wc2f[f * 64 + lane] = __builtin_bit_cast(uint4, vc);
      }
#pragma unroll
      for (int ks = 0; ks < 2; ++ks)
#pragma unroll
        for (int nh = 0; nh < 2; ++nh) {
          f16x8 vv;
#pragma unroll
          for (int i = 0; i < 8; ++i)
            vv[i] = (_Float16)Wg1[(ks * 32 + chunk * 8 + i) * 32 + nh * 16 + n15];
          Wg1f[(ks * 2 + nh) * 64 + lane] = __builtin_bit_cast(uint4, vv);
        }
    }
  }
}

// ---- scanA: bucketBase + per-(chunk,bucket) offsets ----
__global__ __launch_bounds__(256) void scanA_kernel(
    const int* __restrict__ histM, int* __restrict__ colOff,
    int* __restrict__ bucketBase)
{
  int j = threadIdx.x, lane = j & 63, w = j >> 6;
  int total = 0;
  if (j < NB)
    for (int i = 0; i < FILL_B; ++i) total += histM[i * NB + j];
  int x = total;
#pragma unroll
  for (int off = 1; off < 64; off <<= 1) {
    int y = __shfl_up(x, off);
    if (lane >= off) x += y;
  }
  __shared__ int ws[4];
  if (lane == 63) ws[w] = x;
  __syncthreads();
  int woff = 0;
#pragma unroll
  for (int k = 0; k < 4; ++k) if (k < w) woff += ws[k];
  int excl = woff + x - total;
  if (j < NB) {
    bucketBase[j] = excl;
    int running = excl;
    for (int i = 0; i < FILL_B; ++i) {
      colOff[i * NB + j] = running;
      running += histM[i * NB + j];
    }
    if (j == NB - 1) bucketBase[NB] = running;   // == N_EDGES
  }
}

// ---- fill2: scatter edges into per-(chunk,bucket) contiguous slots ----
__global__ __launch_bounds__(256) void fill2_kernel(
    const int* __restrict__ src, const int* __restrict__ dst,
    const int* __restrict__ colOff, uint2* __restrict__ cem)
{
  __shared__ int cur[NB];
  int tid = threadIdx.x, bid = blockIdx.x;
  if (tid < NB) cur[tid] = colOff[bid * NB + tid];
  __syncthreads();
  int ebase = bid * FILL_CHUNK;
#pragma unroll
  for (int it = 0; it < FILL_CHUNK / 256; ++it) {
    int e = ebase + it * 256 + tid;
    if (e < N_EDGES) {
      int s = src[e], d = dst[e];
      int pos = atomicAdd(&cur[d >> 8], 1);
      cem[pos] = make_uint2((unsigned)s, ((unsigned)(d & 255) << 20) | (unsigned)e);
    }
  }
}

// ---- fill3: per-bucket counting sort -> packed ce {src|d<<16, eid}, col16, rowptr ----
__global__ __launch_bounds__(256) void fill3_kernel(
    const uint2* __restrict__ cem, const int* __restrict__ bucketBase,
    uint2* __restrict__ ce, unsigned short* __restrict__ col16,
    int* __restrict__ rowptr)
{
  __shared__ int cnt[256], curs[256], ws[4];
  int j = blockIdx.x, tid = threadIdx.x;
  int base = bucketBase[j], endb = bucketBase[j + 1];
  cnt[tid] = 0;
  __syncthreads();
  for (int k = base + tid; k < endb; k += 256)
    atomicAdd(&cnt[(cem[k].y >> 20) & 255], 1);
  __syncthreads();
  int v = cnt[tid];
  int lane = tid & 63, w = tid >> 6;
  int x = v;
#pragma unroll
  for (int off = 1; off < 64; off <<= 1) {
    int y = __shfl_up(x, off);
    if (lane >= off) x += y;
  }
  if (lane == 63) ws[w] = x;
  __syncthreads();
  int woff = 0;
#pragma unroll
  for (int k = 0; k < 4; ++k) if (k < w) woff += ws[k];
  int ex = woff + x - v;        // exclusive prefix within bucket
  curs[tid] = ex;
  int n = j * 256 + tid;
  if (n < N_NODES) {
    rowptr[n + 1] = base + ex + v;
    if (n == 0) rowptr[0] = 0;
  }
  __syncthreads();
  for (int k = base + tid; k < endb; k += 256) {
    uint2 r = cem[k];
    int dlow = (r.y >> 20) & 255;
    int pos = base + atomicAdd(&curs[dlow], 1);
    unsigned d = (unsigned)(j * 256 + dlow);
    ce[pos] = make_uint2(r.x | (d << 16), r.y & 0xFFFFFu);
    col16[pos] = (unsigned short)r.x;
  }
}

// ---- gather1: T16[n] = x16[n] + sum x16[src]; uint4 rows, 8 edges/iter ----
__global__ __launch_bounds__(256) void gather1_kernel(
    const unsigned* __restrict__ X16, const int* __restrict__ rowptr,
    const unsigned short* __restrict__ col16, unsigned* __restrict__ T16)
{
  int w = threadIdx.x >> 6, lane = threadIdx.x & 63;
  int n = blockIdx.x * 4 + w;
  if (n >= N_NODES) return;
  int beg = rowptr[n], end = rowptr[n + 1];
  int q = lane >> 3, c = lane & 7;
  const uint4* feat4 = (const uint4*)X16;
  float a[8] = {0.f, 0.f, 0.f, 0.f, 0.f, 0.f, 0.f, 0.f};
  for (int k0 = beg; k0 < end; k0 += 64) {
    int kk = k0 + lane;
    int cv = (kk < end) ? (int)col16[kk] : 0;
    int m = end - k0; if (m > 64) m = 64;
    int e = 0;
#pragma unroll 2
    for (; e + 7 < m; e += 8) {
      int se = __shfl(cv, e + q);
      acc8(a, feat4[(size_t)se * 8 + c]);
    }
    int r = m - e;
    if (r) {
      int idx = e + q; if (idx >= m) idx = m - 1;
      int se = __shfl(cv, idx);
      uint4 v = feat4[(size_t)se * 8 + c];
      if (q < r) acc8(a, v);
    }
  }
#pragma unroll
  for (int j = 0; j < 8; ++j) {
    a[j] += __shfl_xor(a[j], 32);
    a[j] += __shfl_xor(a[j], 16);
    a[j] += __shfl_xor(a[j], 8);
  }
  if (q == 0) {
    uint4 xv = ((const uint4*)X16)[(size_t)n * 8 + c];
    float2 x0 = unpackh2(xv.x), x1 = unpackh2(xv.y);
    float2 x2 = unpackh2(xv.z), x3 = unpackh2(xv.w);
    uint4 o;
    o.x = packh2(a[0] + x0.x, a[1] + x0.y);
    o.y = packh2(a[2] + x1.x, a[3] + x1.y);
    o.z = packh2(a[4] + x2.x, a[5] + x2.y);
    o.w = packh2(a[6] + x3.x, a[7] + x3.y);
    ((uint4*)T16)[(size_t)n * 8 + c] = o;
  }
}

// ---- gather2: H2[n] = sig(Q2[n] + sum Q2[src] + bn2); 8 edges/iter ----
__global__ __launch_bounds__(256) void gather2_kernel(
    const unsigned* __restrict__ Q2u, const int* __restrict__ rowptr,
    const unsigned short* __restrict__ col16, const float* __restrict__ bn2,
    unsigned* __restrict__ H2)
{
  int w = threadIdx.x >> 6, lane = threadIdx.x & 63;
  int n = blockIdx.x * 4 + w;
  if (n >= N_NODES) return;
  int beg = rowptr[n], end = rowptr[n + 1];
  int q = lane >> 3, c = lane & 7;
  const uint4* feat4 = (const uint4*)Q2u;
  float a[8] = {0.f, 0.f, 0.f, 0.f, 0.f, 0.f, 0.f, 0.f};
  for (int k0 = beg; k0 < end; k0 += 64) {
    int kk = k0 + lane;
    int cv = (kk < end) ? (int)col16[kk] : 0;
    int m = end - k0; if (m > 64) m = 64;
    int e = 0;
#pragma unroll 2
    for (; e + 7 < m; e += 8) {
      int se = __shfl(cv, e + q);
      acc8(a, feat4[(size_t)se * 8 + c]);
    }
    int r = m - e;
    if (r) {
      int idx = e + q; if (idx >= m) idx = m - 1;
      int se = __shfl(cv, idx);
      uint4 v = feat4[(size_t)se * 8 + c];
      if (q < r) acc8(a, v);
    }
  }
#pragma unroll
  for (int j = 0; j < 8; ++j) {
    a[j] += __shfl_xor(a[j], 32);
    a[j] += __shfl_xor(a[j], 16);
    a[j] += __shfl_xor(a[j], 8);
  }
  if (q == 0) {
    uint4 qv = ((const uint4*)Q2u)[(size_t)n * 8 + c];
    float4 bnA = ((const float4*)bn2)[2 * c];
    float4 bnB = ((const float4*)bn2)[2 * c + 1];
    float2 q0 = unpackh2(qv.x), q1 = unpackh2(qv.y);
    float2 q2 = unpackh2(qv.z), q3 = unpackh2(qv.w);
    uint4 o;
    o.x = packh2(sigf(a[0] + q0.x + bnA.x), sigf(a[1] + q0.y + bnA.y));
    o.y = packh2(sigf(a[2] + q1.x + bnA.z), sigf(a[3] + q1.y + bnA.w));
    o.z = packh2(sigf(a[4] + q2.x + bnB.x), sigf(a[5] + q2.y + bnB.y));
    o.w = packh2(sigf(a[6] + q3.x + bnB.z), sigf(a[7] + q3.y + bnB.w));
    ((uint4*)H2)[(size_t)n * 8 + c] = o;
  }
}

// ---- gather3 + node3 fused: 16 edges/iter ----
__global__ __launch_bounds__(256) void gather3_kernel(
    const unsigned* __restrict__ Q3u, const int* __restrict__ rowptr,
    const unsigned short* __restrict__ col16, const float* __restrict__ bn3,
    const float* __restrict__ Wc3, _Float16* __restrict__ P3h)
{
  int w = threadIdx.x >> 6, lane = threadIdx.x & 63;
  int n = blockIdx.x * 4 + w;
  if (n >= N_NODES) return;
  int beg = rowptr[n], end = rowptr[n + 1];
  int q = lane >> 2, c = lane & 3;
  const uint4* feat4 = (const uint4*)Q3u;
  float a[8] = {0.f, 0.f, 0.f, 0.f, 0.f, 0.f, 0.f, 0.f};
  for (int k0 = beg; k0 < end; k0 += 64) {
    int kk = k0 + lane;
    int cv = (kk < end) ? (int)col16[kk] : 0;
    int m = end - k0; if (m > 64) m = 64;
    int e = 0;
#pragma unroll 2
    for (; e + 15 < m; e += 16) {
      int se = __shfl(cv, e + q);
      acc8(a, feat4[(size_t)se * 4 + c]);
    }
    int r = m - e;
    if (r) {
      int idx = e + q; if (idx >= m) idx = m - 1;
      int se = __shfl(cv, idx);
      uint4 v = feat4[(size_t)se * 4 + c];
      if (q < r) acc8(a, v);
    }
  }
#pragma unroll
  for (int j = 0; j < 8; ++j) {
    a[j] += __shfl_xor(a[j], 32);
    a[j] += __shfl_xor(a[j], 16);
    a[j] += __shfl_xor(a[j], 8);
    a[j] += __shfl_xor(a[j], 4);
  }
  if (q == 0) {
    uint4 qv = feat4[(size_t)n * 4 + c];
    float4 bnA = ((const float4*)bn3)[2 * c], bnB = ((const float4*)bn3)[2 * c + 1];
    float4 wcA = ((const float4*)Wc3)[2 * c], wcB = ((const float4*)Wc3)[2 * c + 1];
    float2 q0 = unpackh2(qv.x), q1 = unpackh2(qv.y);
    float2 q2 = unpackh2(qv.z), q3 = unpackh2(qv.w);
    float p = sigf(a[0] + q0.x + bnA.x) * wcA.x + sigf(a[1] + q0.y + bnA.y) * wcA.y
            + sigf(a[2] + q1.x + bnA.z) * wcA.z + sigf(a[3] + q1.y + bnA.w) * wcA.w
            + sigf(a[4] + q2.x + bnB.x) * wcB.x + sigf(a[5] + q2.y + bnB.y) * wcB.y
            + sigf(a[6] + q3.x + bnB.z) * wcB.z + sigf(a[7] + q3.y + bnB.w) * wcB.w;
    p += __shfl_xor(p, 1); p += __shfl_xor(p, 2);
    if (c == 0) P3h[n] = (_Float16)p;
  }
}

// ---- node layer 1 (MFMA) ----
__global__ __launch_bounds__(256) void node1_kernel(
    const unsigned* __restrict__ T16,
    const uint4* __restrict__ Wn1f, const uint4* __restrict__ Wn2f,
    const uint4* __restrict__ Wc1f, const float* __restrict__ bn1,
    _Float16* __restrict__ Q2h, _Float16* __restrict__ P1h)
{
  __shared__ __align__(16) _Float16 t_lds[64 * 72];
  __shared__ __align__(16) _Float16 h1_lds[64 * 136];
  int tid = threadIdx.x;
  int lane = tid & 63, w = tid >> 6;
  int nbase = blockIdx.x * 64;

#pragma unroll
  for (int rep = 0; rep < 2; ++rep) {
    int uidx = rep * 1024 + tid * 4;
    int node = uidx >> 5, c = uidx & 31;
    int gn = nbase + node; if (gn > N_NODES - 1) gn = N_NODES - 1;
    uint4 tv = *(const uint4*)(T16 + (size_t)gn * 32 + c);
    *(uint4*)(t_lds + node * 72 + c * 2) = tv;
  }
  __syncthreads();

  int row16 = lane & 15, chunk = lane >> 4;
  uint4 b1[2][2];
#pragma unroll
  for (int ntl = 0; ntl < 2; ++ntl)
#pragma unroll
    for (int ks = 0; ks < 2; ++ks)
      b1[ntl][ks] = Wn1f[((2 * w + ntl) * 2 + ks) * 64 + lane];

  f32x4 acc[4][2];
#pragma unroll
  for (int mt = 0; mt < 4; ++mt)
#pragma unroll
    for (int ntl = 0; ntl < 2; ++ntl) acc[mt][ntl] = (f32x4){0.f, 0.f, 0.f, 0.f};
#pragma unroll
  for (int mt = 0; mt < 4; ++mt) {
    const _Float16* ab = t_lds + (mt * 16 + row16) * 72 + chunk * 8;
    f16x8 A0 = *(const f16x8*)ab;
    f16x8 A1 = *(const f16x8*)(ab + 32);
#pragma unroll
    for (int ntl = 0; ntl < 2; ++ntl) {
      acc[mt][ntl] = MFMA16(A0, b1[ntl][0], acc[mt][ntl]);
      acc[mt][ntl] = MFMA16(A1, b1[ntl][1], acc[mt][ntl]);
    }
  }
  float bnv0 = bn1[w * 32 + row16], bnv1 = bn1[w * 32 + 16 + row16];
#pragma unroll
  for (int mt = 0; mt < 4; ++mt)
#pragma unroll
    for (int r = 0; r < 4; ++r) {
      int rowl = mt * 16 + chunk * 4 + r;
      h1_lds[rowl * 136 + w * 32 + row16]      = (_Float16)sigf(acc[mt][0][r] + bnv0);
      h1_lds[rowl * 136 + w * 32 + 16 + row16] = (_Float16)sigf(acc[mt][1][r] + bnv1);
    }
  __syncthreads();

#pragma unroll
  for (int job = 0; job < 2; ++job) {
    const uint4* Wf = job ? Wc1f : Wn2f;
    uint4 bf[4];
#pragma unroll
    for (int ks = 0; ks < 4; ++ks) bf[ks] = Wf[(w * 4 + ks) * 64 + lane];
    f32x4 a2[4];
#pragma unroll
    for (int mt = 0; mt < 4; ++mt) a2[mt] = (f32x4){0.f, 0.f, 0.f, 0.f};
#pragma unroll
    for (int mt = 0; mt < 4; ++mt) {
      const _Float16* hb = h1_lds + (mt * 16 + row16) * 136 + chunk * 8;
#pragma unroll
      for (int ks = 0; ks < 4; ++ks) {
        f16x8 A = *(const f16x8*)(hb + ks * 32);
        a2[mt] = MFMA16(A, bf[ks], a2[mt]);
      }
    }
    _Float16* op = job ? P1h : Q2h;
#pragma unroll
    for (int mt = 0; mt < 4; ++mt)
#pragma unroll
      for (int r = 0; r < 4; ++r) {
        int gn = nbase + mt * 16 + chunk * 4 + r;
        if (gn < N_NODES) op[(size_t)gn * 64 + w * 16 + row16] = (_Float16)a2[mt][r];
      }
  }
}

// ---- node layer 2 (MFMA) ----
__global__ __launch_bounds__(256) void node2_kernel(
    const unsigned* __restrict__ H2,
    const uint4* __restrict__ Wn3f, const uint4* __restrict__ Wc2f,
    _Float16* __restrict__ Q3h, _Float16* __restrict__ P2h)
{
  __shared__ __align__(16) _Float16 t_lds[64 * 72];
  int tid = threadIdx.x, lane = tid & 63, w = tid >> 6;
  int nbase = blockIdx.x * 64;
#pragma unroll
  for (int rep = 0; rep < 2; ++rep) {
    int uidx = rep * 1024 + tid * 4;
    int node = uidx >> 5, c = uidx & 31;
    int gn = nbase + node; if (gn > N_NODES - 1) gn = N_NODES - 1;
    uint4 tv = *(const uint4*)(H2 + (size_t)gn * 32 + c);
    *(uint4*)(t_lds + node * 72 + c * 2) = tv;
  }
  __syncthreads();
  int row16 = lane & 15, chunk = lane >> 4;
  int mat = w >> 1, nt = w & 1;
  const uint4* Wf = mat ? Wc2f : Wn3f;
  uint4 bf0 = Wf[(nt * 2 + 0) * 64 + lane];
  uint4 bf1 = Wf[(nt * 2 + 1) * 64 + lane];
  f32x4 a2[4];
#pragma unroll
  for (int mt = 0; mt < 4; ++mt) a2[mt] = (f32x4){0.f, 0.f, 0.f, 0.f};
#pragma unroll
  for (int mt = 0; mt < 4; ++mt) {
    const _Float16* ab = t_lds + (mt * 16 + row16) * 72 + chunk * 8;
    f16x8 A0 = *(const f16x8*)ab;
    f16x8 A1 = *(const f16x8*)(ab + 32);
    a2[mt] = MFMA16(A0, bf0, a2[mt]);
    a2[mt] = MFMA16(A1, bf1, a2[mt]);
  }
  _Float16* op = mat ? P2h : Q3h;
#pragma unroll
  for (int mt = 0; mt < 4; ++mt)
#pragma unroll
    for (int r = 0; r < 4; ++r) {
      int gn = nbase + mt * 16 + chunk * 4 + r;
      if (gn < N_NODES) op[(size_t)gn * 32 + nt * 16 + row16] = (_Float16)a2[mt][r];
    }
}

// ---- edge kernel: CSR-ordered edges, packed {src|d<<16, eid}, MFMA ----
__global__ __launch_bounds__(256) void edge_kernel(
    const uint2* __restrict__ ce,
    const unsigned* __restrict__ P1_16, const unsigned* __restrict__ P2_16,
    const _Float16* __restrict__ P3_16, const uint4* __restrict__ Bfrag,
    const float* __restrict__ bc1, const float* __restrict__ bc2,
    const float* __restrict__ bc3, const float* __restrict__ bg1,
    const float* __restrict__ Wg2, const float* __restrict__ bg2,
    float* __restrict__ out)
{
  __shared__ __align__(16) _Float16 sbuf[4][32 * 104];
  __shared__ int eidx[4][64];
  __shared__ int eido[4][32];
  int lane = threadIdx.x & 63;
  int w = threadIdx.x >> 6;
  // XCD-bijective block swizzle: nwg=6250 = 8*781+2
  int b = blockIdx.x;
  int xcd = b & 7, idx = b >> 3;
  int swz = (xcd < 2 ? xcd * 782 : 2 * 782 + (xcd - 2) * 781) + idx;
  int ebase = swz * 128 + w * 32;
  _Float16* wb = &sbuf[w][0];

  int e32 = lane & 31;
  uint2 cv2 = ce[ebase + e32];               // all 64 lanes, same 32 entries
  int sv = (int)(cv2.x & 0xFFFFu);
  int dv = (int)(cv2.x >> 16);
  int myi = (lane < 32) ? sv : dv;
  eidx[w][lane] = myi;
  if (lane < 32) eido[w][e32] = (int)cv2.y;

  f16x8 Bf[2][2];
#pragma unroll
  for (int ks = 0; ks < 2; ++ks)
#pragma unroll
    for (int nh = 0; nh < 2; ++nh)
      Bf[ks][nh] = __builtin_bit_cast(f16x8, Bfrag[(ks * 2 + nh) * 64 + lane]);

  {
    float p3v = (float)P3_16[myi];
    float pair = __shfl_xor(p3v, 32);
    if (lane < 32) wb[e32 * 104 + 96] = (_Float16)(p3v + pair);
  }
  // c1: 8 edges / iter, uint4 (8 f16) per lane
  {
    int c = lane & 7, q = lane >> 3;
    unsigned b10 = packh2(bc1[8 * c],     bc1[8 * c + 1]);
    unsigned b11 = packh2(bc1[8 * c + 2], bc1[8 * c + 3]);
    unsigned b12 = packh2(bc1[8 * c + 4], bc1[8 * c + 5]);
    unsigned b13 = packh2(bc1[8 * c + 6], bc1[8 * c + 7]);
#pragma unroll
    for (int it = 0; it < 4; ++it) {
      int e = 8 * it + q;
      int s = eidx[w][e];
      int d = eidx[w][32 + e];
      uint4 ps = *(const uint4*)(P1_16 + (size_t)s * 32 + 4 * c);
      uint4 pd = *(const uint4*)(P1_16 + (size_t)d * 32 + 4 * c);
      h2 v0 = __builtin_bit_cast(h2, addpk(addpk(ps.x, pd.x), b10));
      h2 v1 = __builtin_bit_cast(h2, addpk(addpk(ps.y, pd.y), b11));
      h2 v2 = __builtin_bit_cast(h2, addpk(addpk(ps.z, pd.z), b12));
      h2 v3 = __builtin_bit_cast(h2, addpk(addpk(ps.w, pd.w), b13));
      uint4 o;
      o.x = packh2(sigf((float)v0.x), sigf((float)v0.y));
      o.y = packh2(sigf((float)v1.x), sigf((float)v1.y));
      o.z = packh2(sigf((float)v2.x), sigf((float)v2.y));
      o.w = packh2(sigf((float)v3.x), sigf((float)v3.y));
      *(uint4*)(wb + e * 104 + 8 * c) = o;
    }
  }
  // c2: 16 edges / iter, uint4 per lane
  {
    int c = lane & 3, q = lane >> 2;
    unsigned b20 = packh2(bc2[8 * c],     bc2[8 * c + 1]);
    unsigned b21 = packh2(bc2[8 * c + 2], bc2[8 * c + 3]);
    unsigned b22 = packh2(bc2[8 * c + 4], bc2[8 * c + 5]);
    unsigned b23 = packh2(bc2[8 * c + 6], bc2[8 * c + 7]);
#pragma unroll
    for (int it = 0; it < 2; ++it) {
      int e = 16 * it + q;
      int s = eidx[w][e];
      int d = eidx[w][32 + e];
      uint4 ps = *(const uint4*)(P2_16 + (size_t)s * 16 + 4 * c);
      uint4 pd = *(const uint4*)(P2_16 + (size_t)d * 16 + 4 * c);
      h2 v0 = __builtin_bit_cast(h2, addpk(addpk(ps.x, pd.x), b20));
      h2 v1 = __builtin_bit_cast(h2, addpk(addpk(ps.y, pd.y), b21));
      h2 v2 = __builtin_bit_cast(h2, addpk(addpk(ps.z, pd.z), b22));
      h2 v3 = __builtin_bit_cast(h2, addpk(addpk(ps.w, pd.w), b23));
      uint4 o;
      o.x = packh2(sigf((float)v0.x), sigf((float)v0.y));
      o.y = packh2(sigf((float)v1.x), sigf((float)v1.y));
      o.z = packh2(sigf((float)v2.x), sigf((float)v2.y));
      o.w = packh2(sigf((float)v3.x), sigf((float)v3.y));
      *(uint4*)(wb + e * 104 + 64 + 8 * c) = o;
    }
  }

  int row = lane & 15, chunk = lane >> 4;
  float bg1v0 = bg1[row], bg1v1 = bg1[16 + row];
  float wg2v0 = Wg2[row], wg2v1 = Wg2[16 + row];
  float bg2v = bg2[0], bc3v = bc3[0];
#pragma unroll
  for (int g = 0; g < 2; ++g) {
    const _Float16* abase = wb + (16 * g + row) * 104 + chunk * 8;
    f16x8 A0 = *(const f16x8*)abase;
    f16x8 A1 = *(const f16x8*)(abase + 32);
    f32x4 acc0 = {0.f, 0.f, 0.f, 0.f}, acc1 = {0.f, 0.f, 0.f, 0.f};
    acc0 = __builtin_amdgcn_mfma_f32_16x16x32_f16(A0, Bf[0][0], acc0, 0, 0, 0);
    acc1 = __builtin_amdgcn_mfma_f32_16x16x32_f16(A0, Bf[0][1], acc1, 0, 0, 0);
    acc0 = __builtin_amdgcn_mfma_f32_16x16x32_f16(A1, Bf[1][0], acc0, 0, 0, 0);
    acc1 = __builtin_amdgcn_mfma_f32_16x16x32_f16(A1, Bf[1][1], acc1, 0, 0, 0);
#pragma unroll
    for (int r = 0; r < 4; ++r) {
      int e = 16 * g + chunk * 4 + r;
      float c2a = (float)wb[e * 104 + 64 + row];
      float c2b = (float)wb[e * 104 + 80 + row];
      float v0 = sigf(acc0[r] + bg1v0 + c2a) * wg2v0;
      float v1 = sigf(acc1[r] + bg1v1 + c2b) * wg2v1;
      float part = v0 + v1;
      part += __shfl_xor(part, 1);
      part += __shfl_xor(part, 2);
      part += __shfl_xor(part, 4);
      part += __shfl_xor(part, 8);
      float c3v = (float)wb[e * 104 + 96];
      if (row == 0)
        out[eido[w][e]] = sigf(part + bg2v + sigf(c3v + bc3v));
    }
  }
}

extern "C" void kernel_launch(void* const* d_in, const int* in_sizes, int n_in,
                              void* d_out, int out_size, void* d_ws, size_t ws_size,
                              hipStream_t stream)
{
  const float* x   = (const float*)d_in[0];
  const int*   src = (const int*)d_in[1];
  const int*   dst = (const int*)d_in[2];
  const float* Wn1 = (const float*)d_in[3];
  const float* bn1 = (const float*)d_in[4];
  const float* Wc1 = (const float*)d_in[5];
  const float* bc1 = (const float*)d_in[6];
  const float* Wn2 = (const float*)d_in[7];
  const float* bn2 = (const float*)d_in[8];
  const float* Wc2 = (const float*)d_in[9];
  const float* bc2 = (const float*)d_in[10];
  const float* Wn3 = (const float*)d_in[11];
  const float* bn3 = (const float*)d_in[12];
  const float* Wc3 = (const float*)d_in[13];
  const float* bc3 = (const float*)d_in[14];
  const float* Wg1 = (const float*)d_in[15];
  const float* bg1 = (const float*)d_in[16];
  const float* Wg2 = (const float*)d_in[17];
  const float* bg2 = (const float*)d_in[18];
  float* out = (float*)d_out;

  char* base = (char*)d_ws;
  unsigned* TMP16 = (unsigned*)base; base += (size_t)N_NODES * 32 * 4;   // T16 / H2
  unsigned* X16   = (unsigned*)base; base += (size_t)N_NODES * 32 * 4;
  unsigned* Q2_16 = (unsigned*)base; base += (size_t)N_NODES * 32 * 4;
  unsigned* P1_16 = (unsigned*)base; base += (size_t)N_NODES * 32 * 4;
  unsigned* Q3_16 = (unsigned*)base; base += (size_t)N_NODES * 16 * 4;
  unsigned* P2_16 = (unsigned*)base; base += (size_t)N_NODES * 16 * 4;
  _Float16* P3_16 = (_Float16*)base; base += ((size_t)N_NODES * 2 + 15) / 16 * 16;
  int* rowptr = (int*)base;          base += (size_t)(N_NODES + 1) * 4 + 12;
  uint2* ce   = (uint2*)base;        base += (size_t)N_EDGES * 8;
  uint2* cem  = (uint2*)base;        base += (size_t)N_EDGES * 8;
  unsigned short* col16 = (unsigned short*)base; base += ((size_t)N_EDGES * 2 + 15) / 16 * 16;
  int* histM  = (int*)base;          base += (size_t)FILL_B * NB * 4;
  int* colOff = (int*)base;          base += (size_t)FILL_B * NB * 4;
  int* bucketBase = (int*)base;      base += (size_t)(NB + 1) * 4 + 12;
  uint4* Wg1f = (uint4*)base;        base += 4 * 64 * 16;
  uint4* Wn1f = (uint4*)base;        base += 16 * 64 * 16;
  uint4* Wn2f = (uint4*)base;        base += 16 * 64 * 16;
  uint4* Wc1f = (uint4*)base;        base += 16 * 64 * 16;
  uint4* Wn3f = (uint4*)base;        base += 4 * 64 * 16;
  uint4* Wc2f = (uint4*)base;        base += 4 * 64 * 16;

  // prep (cvt + hist + frag-pack) and radix CSR build
  prep_kernel<<<CVT_B + FILL_B + 1, 256, 0, stream>>>(x, X16, dst, histM,
      Wn1, Wn2, Wc1, Wn3, Wc2, Wg1, Wn1f, Wn2f, Wc1f, Wn3f, Wc2f, Wg1f);
  scanA_kernel<<<1, 256, 0, stream>>>(histM, colOff, bucketBase);
  fill2_kernel<<<FILL_B, 256, 0, stream>>>(src, dst, colOff, cem);
  fill3_kernel<<<NB, 256, 0, stream>>>(cem, bucketBase, ce, col16, rowptr);

  // layer 1: T16 = x + agg(x); node1 -> Q2, P1
  gather1_kernel<<<(N_NODES + 3) / 4, 256, 0, stream>>>(X16, rowptr, col16, TMP16);
  node1_kernel<<<NODE_B, 256, 0, stream>>>(TMP16, Wn1f, Wn2f, Wc1f, bn1,
      (_Float16*)Q2_16, (_Float16*)P1_16);
  // layer 2: H2 = sig(Q2 + agg(Q2) + bn2); node2 -> Q3, P2
  gather2_kernel<<<(N_NODES + 3) / 4, 256, 0, stream>>>(Q2_16, rowptr, col16, bn2, TMP16);
  node2_kernel<<<NODE_B, 256, 0, stream>>>(TMP16, Wn3f, Wc2f,
      (_Float16*)Q3_16, (_Float16*)P2_16);
  // layer 3 (gather + node3 fused) -> P3
  gather3_kernel<<<(N_NODES + 3) / 4, 256, 0, stream>>>(Q3_16, rowptr, col16, bn3, Wc3, P3_16);
  // edge-level epilogue in CSR (dst-sorted) order
  edge_kernel<<<EDGE_B, 256, 0, stream>>>(ce, P1_16, P2_16, P3_16, Wg1f,
      bc1, bc2, bc3, bg1, Wg2, bg2, out);
}

// Round 14
// 171.955 us; speedup vs baseline: 1.5352x; 1.0353x over previous
//
#include <hip/hip_runtime.h>

#define N_NODES 50000
#define N_EDGES 800000
#define CVT_B 6250                          // N_NODES*32/256
#define NODE_B ((N_NODES + 63) / 64)        // 782
#define EDGE_B2 (N_EDGES / 64)              // 12500 (2-wave blocks)
#define NB 196                              // dst buckets (256 nodes each)
#define FILL_B 196                          // edge chunks of 4096
#define FILL_CHUNK 4096

typedef _Float16 h2 __attribute__((ext_vector_type(2)));
typedef _Float16 f16x8 __attribute__((ext_vector_type(8)));
typedef float f32x4 __attribute__((ext_vector_type(4)));

__device__ __forceinline__ float sigf(float v) {
  return __builtin_amdgcn_rcpf(1.0f + __expf(-v));
}
__device__ __forceinline__ unsigned packh2(float a, float b) {
  return __builtin_bit_cast(unsigned, __builtin_amdgcn_cvt_pkrtz(a, b));
}
__device__ __forceinline__ float2 unpackh2(unsigned u) {
  h2 p = __builtin_bit_cast(h2, u);
  return make_float2((float)p.x, (float)p.y);
}
__device__ __forceinline__ void acc8(float* a, uint4 v) {
  float2 p0 = unpackh2(v.x), p1 = unpackh2(v.y);
  float2 p2 = unpackh2(v.z), p3 = unpackh2(v.w);
  a[0] += p0.x; a[1] += p0.y; a[2] += p1.x; a[3] += p1.y;
  a[4] += p2.x; a[5] += p2.y; a[6] += p3.x; a[7] += p3.y;
}
__device__ __forceinline__ unsigned addpk(unsigned a, unsigned b) {
  h2 r = __builtin_bit_cast(h2, a) + __builtin_bit_cast(h2, b);
  return __builtin_bit_cast(unsigned, r);
}
#define MFMA16(A, B, C) __builtin_amdgcn_mfma_f32_16x16x32_f16(A, __builtin_bit_cast(f16x8, B), C, 0, 0, 0)

// ---- prep: x->f16 | per-chunk dst histogram | weights -> MFMA B-frag ----
__global__ __launch_bounds__(256) void prep_kernel(
    const float* __restrict__ x, unsigned* __restrict__ x16,
    const int* __restrict__ dst, int* __restrict__ histM,
    const float* __restrict__ Wn1, const float* __restrict__ Wn2,
    const float* __restrict__ Wc1, const float* __restrict__ Wn3,
    const float* __restrict__ Wc2, const float* __restrict__ Wg1,
    uint4* __restrict__ Wn1f, uint4* __restrict__ Wn2f, uint4* __restrict__ Wc1f,
    uint4* __restrict__ Wn3f, uint4* __restrict__ Wc2f, uint4* __restrict__ Wg1f)
{
  int b = blockIdx.x;
  if (b < CVT_B) {
    int i = b * 256 + threadIdx.x;
    float2 v = ((const float2*)x)[i];
    x16[i] = packh2(v.x, v.y);
  } else if (b < CVT_B + FILL_B) {
    __shared__ int hist[NB];
    int tid = threadIdx.x, bid = b - CVT_B;
    if (tid < NB) hist[tid] = 0;
    __syncthreads();
    int ebase = bid * FILL_CHUNK;
#pragma unroll
    for (int it = 0; it < FILL_CHUNK / 256; ++it) {
      int e = ebase + it * 256 + tid;
      if (e < N_EDGES) atomicAdd(&hist[dst[e] >> 8], 1);
    }
    __syncthreads();
    if (tid < NB) histM[bid * NB + tid] = hist[tid];
  } else {
    int lane = threadIdx.x & 63, w = threadIdx.x >> 6;
    int n15 = lane & 15, chunk = lane >> 4;
    if (w == 0) {           // Wn1f: K=64, N=128 -> 8 nt x 2 ks
#pragma unroll
      for (int f = 0; f < 16; ++f) {
        int nt = f >> 1, ks = f & 1;
        int n = nt * 16 + n15;
        f16x8 vv;
#pragma unroll
        for (int i = 0; i < 8; ++i) vv[i] = (_Float16)Wn1[(ks * 32 + chunk * 8 + i) * 128 + n];
        Wn1f[f * 64 + lane] = __builtin_bit_cast(uint4, vv);
      }
    } else if (w == 1) {    // Wn2f: K=128, N=64 -> 4 nt x 4 ks
#pragma unroll
      for (int f = 0; f < 16; ++f) {
        int nt = f >> 2, ks = f & 3;
        int n = nt * 16 + n15;
        f16x8 vv;
#pragma unroll
        for (int i = 0; i < 8; ++i) vv[i] = (_Float16)Wn2[(ks * 32 + chunk * 8 + i) * 64 + n];
        Wn2f[f * 64 + lane] = __builtin_bit_cast(uint4, vv);
      }
    } else if (w == 2) {    // Wc1f: K=128, N=64 -> 4 nt x 4 ks
#pragma unroll
      for (int f = 0; f < 16; ++f) {
        int nt = f >> 2, ks = f & 3;
        int n = nt * 16 + n15;
        f16x8 vv;
#pragma unroll
        for (int i = 0; i < 8; ++i) vv[i] = (_Float16)Wc1[(ks * 32 + chunk * 8 + i) * 64 + n];
        Wc1f[f * 64 + lane] = __builtin_bit_cast(uint4, vv);
      }
    } else {                // Wn3f, Wc2f: K=64,N=32; Wg1f
#pragma unroll
      for (int f = 0; f < 4; ++f) {
        int nt = f >> 1, ks = f & 1;
        int n = nt * 16 + n15;
        f16x8 v3, vc;
#pragma unroll
        for (int i = 0; i < 8; ++i) {
          int k = ks * 32 + chunk * 8 + i;
          v3[i] = (_Float16)Wn3[k * 32 + n];
          vc[i] = (_Float16)Wc2[k * 32 + n];
        }
        Wn3f[f * 64 + lane] = __builtin_bit_cast(uint4, v3);
        Wc2f[f * 64 + lane] = __builtin_bit_cast(uint4, vc);
      }
#pragma unroll
      for (int ks = 0; ks < 2; ++ks)
#pragma unroll
        for (int nh = 0; nh < 2; ++nh) {
          f16x8 vv;
#pragma unroll
          for (int i = 0; i < 8; ++i)
            vv[i] = (_Float16)Wg1[(ks * 32 + chunk * 8 + i) * 32 + nh * 16 + n15];
          Wg1f[(ks * 2 + nh) * 64 + lane] = __builtin_bit_cast(uint4, vv);
        }
    }
  }
}

// ---- scanA1: per-bucket exclusive scan over chunks (parallel, NB blocks) ----
__global__ __launch_bounds__(256) void scanA1_kernel(
    const int* __restrict__ histM, int* __restrict__ colOff,
    int* __restrict__ colTot)
{
  int j = blockIdx.x;            // bucket
  int i = threadIdx.x;           // chunk
  int lane = i & 63, w = i >> 6;
  int v = (i < FILL_B) ? histM[i * NB + j] : 0;
  int x = v;
#pragma unroll
  for (int off = 1; off < 64; off <<= 1) {
    int y = __shfl_up(x, off);
    if (lane >= off) x += y;
  }
  __shared__ int ws[4];
  if (lane == 63) ws[w] = x;
  __syncthreads();
  int woff = 0;
#pragma unroll
  for (int k = 0; k < 4; ++k) if (k < w) woff += ws[k];
  int excl = woff + x - v;
  if (i < FILL_B) colOff[i * NB + j] = excl;
  if (i == FILL_B - 1) colTot[j] = excl + v;
}

// ---- scanA2: scan bucket totals -> bucketBase ----
__global__ __launch_bounds__(256) void scanA2_kernel(
    const int* __restrict__ colTot, int* __restrict__ bucketBase)
{
  int j = threadIdx.x, lane = j & 63, w = j >> 6;
  int v = (j < NB) ? colTot[j] : 0;
  int x = v;
#pragma unroll
  for (int off = 1; off < 64; off <<= 1) {
    int y = __shfl_up(x, off);
    if (lane >= off) x += y;
  }
  __shared__ int ws[4];
  if (lane == 63) ws[w] = x;
  __syncthreads();
  int woff = 0;
#pragma unroll
  for (int k = 0; k < 4; ++k) if (k < w) woff += ws[k];
  int excl = woff + x - v;
  if (j < NB) bucketBase[j] = excl;
  if (j == NB - 1) bucketBase[NB] = excl + v;
}

// ---- fill2: scatter edges into per-(chunk,bucket) contiguous slots ----
__global__ __launch_bounds__(256) void fill2_kernel(
    const int* __restrict__ src, const int* __restrict__ dst,
    const int* __restrict__ colOff, const int* __restrict__ bucketBase,
    uint2* __restrict__ cem)
{
  __shared__ int cur[NB];
  int tid = threadIdx.x, bid = blockIdx.x;
  if (tid < NB) cur[tid] = colOff[bid * NB + tid] + bucketBase[tid];
  __syncthreads();
  int ebase = bid * FILL_CHUNK;
#pragma unroll
  for (int it = 0; it < FILL_CHUNK / 256; ++it) {
    int e = ebase + it * 256 + tid;
    if (e < N_EDGES) {
      int s = src[e], d = dst[e];
      int pos = atomicAdd(&cur[d >> 8], 1);
      cem[pos] = make_uint2((unsigned)s, ((unsigned)(d & 255) << 20) | (unsigned)e);
    }
  }
}

// ---- fill3: per-bucket counting sort -> packed ce {src|d<<16, eid}, col16, rowptr ----
__global__ __launch_bounds__(256) void fill3_kernel(
    const uint2* __restrict__ cem, const int* __restrict__ bucketBase,
    uint2* __restrict__ ce, unsigned short* __restrict__ col16,
    int* __restrict__ rowptr)
{
  __shared__ int cnt[256], curs[256], ws[4];
  int j = blockIdx.x, tid = threadIdx.x;
  int base = bucketBase[j], endb = bucketBase[j + 1];
  cnt[tid] = 0;
  __syncthreads();
  for (int k = base + tid; k < endb; k += 256)
    atomicAdd(&cnt[(cem[k].y >> 20) & 255], 1);
  __syncthreads();
  int v = cnt[tid];
  int lane = tid & 63, w = tid >> 6;
  int x = v;
#pragma unroll
  for (int off = 1; off < 64; off <<= 1) {
    int y = __shfl_up(x, off);
    if (lane >= off) x += y;
  }
  if (lane == 63) ws[w] = x;
  __syncthreads();
  int woff = 0;
#pragma unroll
  for (int k = 0; k < 4; ++k) if (k < w) woff += ws[k];
  int ex = woff + x - v;        // exclusive prefix within bucket
  curs[tid] = ex;
  int n = j * 256 + tid;
  if (n < N_NODES) {
    rowptr[n + 1] = base + ex + v;
    if (n == 0) rowptr[0] = 0;
  }
  __syncthreads();
  for (int k = base + tid; k < endb; k += 256) {
    uint2 r = cem[k];
    int dlow = (r.y >> 20) & 255;
    int pos = base + atomicAdd(&curs[dlow], 1);
    unsigned d = (unsigned)(j * 256 + dlow);
    ce[pos] = make_uint2(r.x | (d << 16), r.y & 0xFFFFFu);
    col16[pos] = (unsigned short)r.x;
  }
}

// ---- gather1: T16[n] = x16[n] + sum x16[src]; uint4 rows, 8 edges/iter ----
__global__ __launch_bounds__(256) void gather1_kernel(
    const unsigned* __restrict__ X16, const int* __restrict__ rowptr,
    const unsigned short* __restrict__ col16, unsigned* __restrict__ T16)
{
  int w = threadIdx.x >> 6, lane = threadIdx.x & 63;
  int n = blockIdx.x * 4 + w;
  if (n >= N_NODES) return;
  int beg = rowptr[n], end = rowptr[n + 1];
  int q = lane >> 3, c = lane & 7;
  const uint4* feat4 = (const uint4*)X16;
  float a[8] = {0.f, 0.f, 0.f, 0.f, 0.f, 0.f, 0.f, 0.f};
  for (int k0 = beg; k0 < end; k0 += 64) {
    int kk = k0 + lane;
    int cv = (kk < end) ? (int)col16[kk] : 0;
    int m = end - k0; if (m > 64) m = 64;
    int e = 0;
#pragma unroll 2
    for (; e + 7 < m; e += 8) {
      int se = __shfl(cv, e + q);
      acc8(a, feat4[(size_t)se * 8 + c]);
    }
    int r = m - e;
    if (r) {
      int idx = e + q; if (idx >= m) idx = m - 1;
      int se = __shfl(cv, idx);
      uint4 v = feat4[(size_t)se * 8 + c];
      if (q < r) acc8(a, v);
    }
  }
#pragma unroll
  for (int j = 0; j < 8; ++j) {
    a[j] += __shfl_xor(a[j], 32);
    a[j] += __shfl_xor(a[j], 16);
    a[j] += __shfl_xor(a[j], 8);
  }
  if (q == 0) {
    uint4 xv = ((const uint4*)X16)[(size_t)n * 8 + c];
    float2 x0 = unpackh2(xv.x), x1 = unpackh2(xv.y);
    float2 x2 = unpackh2(xv.z), x3 = unpackh2(xv.w);
    uint4 o;
    o.x = packh2(a[0] + x0.x, a[1] + x0.y);
    o.y = packh2(a[2] + x1.x, a[3] + x1.y);
    o.z = packh2(a[4] + x2.x, a[5] + x2.y);
    o.w = packh2(a[6] + x3.x, a[7] + x3.y);
    ((uint4*)T16)[(size_t)n * 8 + c] = o;
  }
}

// ---- gather2: H2[n] = sig(Q2[n] + sum Q2[src] + bn2); 8 edges/iter ----
__global__ __launch_bounds__(256) void gather2_kernel(
    const unsigned* __restrict__ Q2u, const int* __restrict__ rowptr,
    const unsigned short* __restrict__ col16, const float* __restrict__ bn2,
    unsigned* __restrict__ H2)
{
  int w = threadIdx.x >> 6, lane = threadIdx.x & 63;
  int n = blockIdx.x * 4 + w;
  if (n >= N_NODES) return;
  int beg = rowptr[n], end = rowptr[n + 1];
  int q = lane >> 3, c = lane & 7;
  const uint4* feat4 = (const uint4*)Q2u;
  float a[8] = {0.f, 0.f, 0.f, 0.f, 0.f, 0.f, 0.f, 0.f};
  for (int k0 = beg; k0 < end; k0 += 64) {
    int kk = k0 + lane;
    int cv = (kk < end) ? (int)col16[kk] : 0;
    int m = end - k0; if (m > 64) m = 64;
    int e = 0;
#pragma unroll 2
    for (; e + 7 < m; e += 8) {
      int se = __shfl(cv, e + q);
      acc8(a, feat4[(size_t)se * 8 + c]);
    }
    int r = m - e;
    if (r) {
      int idx = e + q; if (idx >= m) idx = m - 1;
      int se = __shfl(cv, idx);
      uint4 v = feat4[(size_t)se * 8 + c];
      if (q < r) acc8(a, v);
    }
  }
#pragma unroll
  for (int j = 0; j < 8; ++j) {
    a[j] += __shfl_xor(a[j], 32);
    a[j] += __shfl_xor(a[j], 16);
    a[j] += __shfl_xor(a[j], 8);
  }
  if (q == 0) {
    uint4 qv = ((const uint4*)Q2u)[(size_t)n * 8 + c];
    float4 bnA = ((const float4*)bn2)[2 * c];
    float4 bnB = ((const float4*)bn2)[2 * c + 1];
    float2 q0 = unpackh2(qv.x), q1 = unpackh2(qv.y);
    float2 q2 = unpackh2(qv.z), q3 = unpackh2(qv.w);
    uint4 o;
    o.x = packh2(sigf(a[0] + q0.x + bnA.x), sigf(a[1] + q0.y + bnA.y));
    o.y = packh2(sigf(a[2] + q1.x + bnA.z), sigf(a[3] + q1.y + bnA.w));
    o.z = packh2(sigf(a[4] + q2.x + bnB.x), sigf(a[5] + q2.y + bnB.y));
    o.w = packh2(sigf(a[6] + q3.x + bnB.z), sigf(a[7] + q3.y + bnB.w));
    ((uint4*)H2)[(size_t)n * 8 + c] = o;
  }
}

// ---- gather3 + node3 fused: 16 edges/iter ----
__global__ __launch_bounds__(256) void gather3_kernel(
    const unsigned* __restrict__ Q3u, const int* __restrict__ rowptr,
    const unsigned short* __restrict__ col16, const float* __restrict__ bn3,
    const float* __restrict__ Wc3, _Float16* __restrict__ P3h)
{
  int w = threadIdx.x >> 6, lane = threadIdx.x & 63;
  int n = blockIdx.x * 4 + w;
  if (n >= N_NODES) return;
  int beg = rowptr[n], end = rowptr[n + 1];
  int q = lane >> 2, c = lane & 3;
  const uint4* feat4 = (const uint4*)Q3u;
  float a[8] = {0.f, 0.f, 0.f, 0.f, 0.f, 0.f, 0.f, 0.f};
  for (int k0 = beg; k0 < end; k0 += 64) {
    int kk = k0 + lane;
    int cv = (kk < end) ? (int)col16[kk] : 0;
    int m = end - k0; if (m > 64) m = 64;
    int e = 0;
#pragma unroll 2
    for (; e + 15 < m; e += 16) {
      int se = __shfl(cv, e + q);
      acc8(a, feat4[(size_t)se * 4 + c]);
    }
    int r = m - e;
    if (r) {
      int idx = e + q; if (idx >= m) idx = m - 1;
      int se = __shfl(cv, idx);
      uint4 v = feat4[(size_t)se * 4 + c];
      if (q < r) acc8(a, v);
    }
  }
#pragma unroll
  for (int j = 0; j < 8; ++j) {
    a[j] += __shfl_xor(a[j], 32);
    a[j] += __shfl_xor(a[j], 16);
    a[j] += __shfl_xor(a[j], 8);
    a[j] += __shfl_xor(a[j], 4);
  }
  if (q == 0) {
    uint4 qv = feat4[(size_t)n * 4 + c];
    float4 bnA = ((const float4*)bn3)[2 * c], bnB = ((const float4*)bn3)[2 * c + 1];
    float4 wcA = ((const float4*)Wc3)[2 * c], wcB = ((const float4*)Wc3)[2 * c + 1];
    float2 q0 = unpackh2(qv.x), q1 = unpackh2(qv.y);
    float2 q2 = unpackh2(qv.z), q3 = unpackh2(qv.w);
    float p = sigf(a[0] + q0.x + bnA.x) * wcA.x + sigf(a[1] + q0.y + bnA.y) * wcA.y
            + sigf(a[2] + q1.x + bnA.z) * wcA.z + sigf(a[3] + q1.y + bnA.w) * wcA.w
            + sigf(a[4] + q2.x + bnB.x) * wcB.x + sigf(a[5] + q2.y + bnB.y) * wcB.y
            + sigf(a[6] + q3.x + bnB.z) * wcB.z + sigf(a[7] + q3.y + bnB.w) * wcB.w;
    p += __shfl_xor(p, 1); p += __shfl_xor(p, 2);
    if (c == 0) P3h[n] = (_Float16)p;
  }
}

// ---- node layer 1 (MFMA) ----
__global__ __launch_bounds__(256) void node1_kernel(
    const unsigned* __restrict__ T16,
    const uint4* __restrict__ Wn1f, const uint4* __restrict__ Wn2f,
    const uint4* __restrict__ Wc1f, const float* __restrict__ bn1,
    _Float16* __restrict__ Q2h, _Float16* __restrict__ P1h)
{
  __shared__ __align__(16) _Float16 t_lds[64 * 72];
  __shared__ __align__(16) _Float16 h1_lds[64 * 136];
  int tid = threadIdx.x;
  int lane = tid & 63, w = tid >> 6;
  int nbase = blockIdx.x * 64;

#pragma unroll
  for (int rep = 0; rep < 2; ++rep) {
    int uidx = rep * 1024 + tid * 4;
    int node = uidx >> 5, c = uidx & 31;
    int gn = nbase + node; if (gn > N_NODES - 1) gn = N_NODES - 1;
    uint4 tv = *(const uint4*)(T16 + (size_t)gn * 32 + c);
    *(uint4*)(t_lds + node * 72 + c * 2) = tv;
  }
  __syncthreads();

  int row16 = lane & 15, chunk = lane >> 4;
  uint4 b1[2][2];
#pragma unroll
  for (int ntl = 0; ntl < 2; ++ntl)
#pragma unroll
    for (int ks = 0; ks < 2; ++ks)
      b1[ntl][ks] = Wn1f[((2 * w + ntl) * 2 + ks) * 64 + lane];

  f32x4 acc[4][2];
#pragma unroll
  for (int mt = 0; mt < 4; ++mt)
#pragma unroll
    for (int ntl = 0; ntl < 2; ++ntl) acc[mt][ntl] = (f32x4){0.f, 0.f, 0.f, 0.f};
#pragma unroll
  for (int mt = 0; mt < 4; ++mt) {
    const _Float16* ab = t_lds + (mt * 16 + row16) * 72 + chunk * 8;
    f16x8 A0 = *(const f16x8*)ab;
    f16x8 A1 = *(const f16x8*)(ab + 32);
#pragma unroll
    for (int ntl = 0; ntl < 2; ++ntl) {
      acc[mt][ntl] = MFMA16(A0, b1[ntl][0], acc[mt][ntl]);
      acc[mt][ntl] = MFMA16(A1, b1[ntl][1], acc[mt][ntl]);
    }
  }
  float bnv0 = bn1[w * 32 + row16], bnv1 = bn1[w * 32 + 16 + row16];
#pragma unroll
  for (int mt = 0; mt < 4; ++mt)
#pragma unroll
    for (int r = 0; r < 4; ++r) {
      int rowl = mt * 16 + chunk * 4 + r;
      h1_lds[rowl * 136 + w * 32 + row16]      = (_Float16)sigf(acc[mt][0][r] + bnv0);
      h1_lds[rowl * 136 + w * 32 + 16 + row16] = (_Float16)sigf(acc[mt][1][r] + bnv1);
    }
  __syncthreads();

#pragma unroll
  for (int job = 0; job < 2; ++job) {
    const uint4* Wf = job ? Wc1f : Wn2f;
    uint4 bf[4];
#pragma unroll
    for (int ks = 0; ks < 4; ++ks) bf[ks] = Wf[(w * 4 + ks) * 64 + lane];
    f32x4 a2[4];
#pragma unroll
    for (int mt = 0; mt < 4; ++mt) a2[mt] = (f32x4){0.f, 0.f, 0.f, 0.f};
#pragma unroll
    for (int mt = 0; mt < 4; ++mt) {
      const _Float16* hb = h1_lds + (mt * 16 + row16) * 136 + chunk * 8;
#pragma unroll
      for (int ks = 0; ks < 4; ++ks) {
        f16x8 A = *(const f16x8*)(hb + ks * 32);
        a2[mt] = MFMA16(A, bf[ks], a2[mt]);
      }
    }
    _Float16* op = job ? P1h : Q2h;
#pragma unroll
    for (int mt = 0; mt < 4; ++mt)
#pragma unroll
      for (int r = 0; r < 4; ++r) {
        int gn = nbase + mt * 16 + chunk * 4 + r;
        if (gn < N_NODES) op[(size_t)gn * 64 + w * 16 + row16] = (_Float16)a2[mt][r];
      }
  }
}

// ---- node layer 2 (MFMA) ----
__global__ __launch_bounds__(256) void node2_kernel(
    const unsigned* __restrict__ H2,
    const uint4* __restrict__ Wn3f, const uint4* __restrict__ Wc2f,
    _Float16* __restrict__ Q3h, _Float16* __restrict__ P2h)
{
  __shared__ __align__(16) _Float16 t_lds[64 * 72];
  int tid = threadIdx.x, lane = tid & 63, w = tid >> 6;
  int nbase = blockIdx.x * 64;
#pragma unroll
  for (int rep = 0; rep < 2; ++rep) {
    int uidx = rep * 1024 + tid * 4;
    int node = uidx >> 5, c = uidx & 31;
    int gn = nbase + node; if (gn > N_NODES - 1) gn = N_NODES - 1;
    uint4 tv = *(const uint4*)(H2 + (size_t)gn * 32 + c);
    *(uint4*)(t_lds + node * 72 + c * 2) = tv;
  }
  __syncthreads();
  int row16 = lane & 15, chunk = lane >> 4;
  int mat = w >> 1, nt = w & 1;
  const uint4* Wf = mat ? Wc2f : Wn3f;
  uint4 bf0 = Wf[(nt * 2 + 0) * 64 + lane];
  uint4 bf1 = Wf[(nt * 2 + 1) * 64 + lane];
  f32x4 a2[4];
#pragma unroll
  for (int mt = 0; mt < 4; ++mt) a2[mt] = (f32x4){0.f, 0.f, 0.f, 0.f};
#pragma unroll
  for (int mt = 0; mt < 4; ++mt) {
    const _Float16* ab = t_lds + (mt * 16 + row16) * 72 + chunk * 8;
    f16x8 A0 = *(const f16x8*)ab;
    f16x8 A1 = *(const f16x8*)(ab + 32);
    a2[mt] = MFMA16(A0, bf0, a2[mt]);
    a2[mt] = MFMA16(A1, bf1, a2[mt]);
  }
  _Float16* op = mat ? P2h : Q3h;
#pragma unroll
  for (int mt = 0; mt < 4; ++mt)
#pragma unroll
    for (int r = 0; r < 4; ++r) {
      int gn = nbase + mt * 16 + chunk * 4 + r;
      if (gn < N_NODES) op[(size_t)gn * 32 + nt * 16 + row16] = (_Float16)a2[mt][r];
    }
}

// ---- edge kernel: 2-wave blocks (higher occupancy), CSR order, MFMA ----
__global__ __launch_bounds__(128) void edge_kernel(
    const uint2* __restrict__ ce,
    const unsigned* __restrict__ P1_16, const unsigned* __restrict__ P2_16,
    const _Float16* __restrict__ P3_16, const uint4* __restrict__ Bfrag,
    const float* __restrict__ bc1, const float* __restrict__ bc2,
    const float* __restrict__ bc3, const float* __restrict__ bg1,
    const float* __restrict__ Wg2, const float* __restrict__ bg2,
    float* __restrict__ out)
{
  __shared__ __align__(16) _Float16 sbuf[2][32 * 104];
  __shared__ int eidx[2][64];
  __shared__ int eido[2][32];
  int lane = threadIdx.x & 63;
  int w = threadIdx.x >> 6;
  // XCD-bijective block swizzle: nwg=12500 = 8*1562+4
  int b = blockIdx.x;
  int xcd = b & 7, idx = b >> 3;
  int swz = (xcd < 4 ? xcd * 1563 : 4 * 1563 + (xcd - 4) * 1562) + idx;
  int ebase = swz * 64 + w * 32;
  _Float16* wb = &sbuf[w][0];

  int e32 = lane & 31;
  uint2 cv2 = ce[ebase + e32];
  int sv = (int)(cv2.x & 0xFFFFu);
  int dv = (int)(cv2.x >> 16);
  int myi = (lane < 32) ? sv : dv;
  eidx[w][lane] = myi;
  if (lane < 32) eido[w][e32] = (int)cv2.y;

  f16x8 Bf[2][2];
#pragma unroll
  for (int ks = 0; ks < 2; ++ks)
#pragma unroll
    for (int nh = 0; nh < 2; ++nh)
      Bf[ks][nh] = __builtin_bit_cast(f16x8, Bfrag[(ks * 2 + nh) * 64 + lane]);

  {
    float p3v = (float)P3_16[myi];
    float pair = __shfl_xor(p3v, 32);
    if (lane < 32) wb[e32 * 104 + 96] = (_Float16)(p3v + pair);
  }
  // c1: 8 edges / iter, uint4 (8 f16) per lane
  {
    int c = lane & 7, q = lane >> 3;
    unsigned b10 = packh2(bc1[8 * c],     bc1[8 * c + 1]);
    unsigned b11 = packh2(bc1[8 * c + 2], bc1[8 * c + 3]);
    unsigned b12 = packh2(bc1[8 * c + 4], bc1[8 * c + 5]);
    unsigned b13 = packh2(bc1[8 * c + 6], bc1[8 * c + 7]);
#pragma unroll
    for (int it = 0; it < 4; ++it) {
      int e = 8 * it + q;
      int s = eidx[w][e];
      int d = eidx[w][32 + e];
      uint4 ps = *(const uint4*)(P1_16 + (size_t)s * 32 + 4 * c);
      uint4 pd = *(const uint4*)(P1_16 + (size_t)d * 32 + 4 * c);
      h2 v0 = __builtin_bit_cast(h2, addpk(addpk(ps.x, pd.x), b10));
      h2 v1 = __builtin_bit_cast(h2, addpk(addpk(ps.y, pd.y), b11));
      h2 v2 = __builtin_bit_cast(h2, addpk(addpk(ps.z, pd.z), b12));
      h2 v3 = __builtin_bit_cast(h2, addpk(addpk(ps.w, pd.w), b13));
      uint4 o;
      o.x = packh2(sigf((float)v0.x), sigf((float)v0.y));
      o.y = packh2(sigf((float)v1.x), sigf((float)v1.y));
      o.z = packh2(sigf((float)v2.x), sigf((float)v2.y));
      o.w = packh2(sigf((float)v3.x), sigf((float)v3.y));
      *(uint4*)(wb + e * 104 + 8 * c) = o;
    }
  }
  // c2: 16 edges / iter, uint4 per lane
  {
    int c = lane & 3, q = lane >> 2;
    unsigned b20 = packh2(bc2[8 * c],     bc2[8 * c + 1]);
    unsigned b21 = packh2(bc2[8 * c + 2], bc2[8 * c + 3]);
    unsigned b22 = packh2(bc2[8 * c + 4], bc2[8 * c + 5]);
    unsigned b23 = packh2(bc2[8 * c + 6], bc2[8 * c + 7]);
#pragma unroll
    for (int it = 0; it < 2; ++it) {
      int e = 16 * it + q;
      int s = eidx[w][e];
      int d = eidx[w][32 + e];
      uint4 ps = *(const uint4*)(P2_16 + (size_t)s * 16 + 4 * c);
      uint4 pd = *(const uint4*)(P2_16 + (size_t)d * 16 + 4 * c);
      h2 v0 = __builtin_bit_cast(h2, addpk(addpk(ps.x, pd.x), b20));
      h2 v1 = __builtin_bit_cast(h2, addpk(addpk(ps.y, pd.y), b21));
      h2 v2 = __builtin_bit_cast(h2, addpk(addpk(ps.z, pd.z), b22));
      h2 v3 = __builtin_bit_cast(h2, addpk(addpk(ps.w, pd.w), b23));
      uint4 o;
      o.x = packh2(sigf((float)v0.x), sigf((float)v0.y));
      o.y = packh2(sigf((float)v1.x), sigf((float)v1.y));
      o.z = packh2(sigf((float)v2.x), sigf((float)v2.y));
      o.w = packh2(sigf((float)v3.x), sigf((float)v3.y));
      *(uint4*)(wb + e * 104 + 64 + 8 * c) = o;
    }
  }

  int row = lane & 15, chunk = lane >> 4;
  float bg1v0 = bg1[row], bg1v1 = bg1[16 + row];
  float wg2v0 = Wg2[row], wg2v1 = Wg2[16 + row];
  float bg2v = bg2[0], bc3v = bc3[0];
#pragma unroll
  for (int g = 0; g < 2; ++g) {
    const _Float16* abase = wb + (16 * g + row) * 104 + chunk * 8;
    f16x8 A0 = *(const f16x8*)abase;
    f16x8 A1 = *(const f16x8*)(abase + 32);
    f32x4 acc0 = {0.f, 0.f, 0.f, 0.f}, acc1 = {0.f, 0.f, 0.f, 0.f};
    acc0 = __builtin_amdgcn_mfma_f32_16x16x32_f16(A0, Bf[0][0], acc0, 0, 0, 0);
    acc1 = __builtin_amdgcn_mfma_f32_16x16x32_f16(A0, Bf[0][1], acc1, 0, 0, 0);
    acc0 = __builtin_amdgcn_mfma_f32_16x16x32_f16(A1, Bf[1][0], acc0, 0, 0, 0);
    acc1 = __builtin_amdgcn_mfma_f32_16x16x32_f16(A1, Bf[1][1], acc1, 0, 0, 0);
#pragma unroll
    for (int r = 0; r < 4; ++r) {
      int e = 16 * g + chunk * 4 + r;
      float c2a = (float)wb[e * 104 + 64 + row];
      float c2b = (float)wb[e * 104 + 80 + row];
      float v0 = sigf(acc0[r] + bg1v0 + c2a) * wg2v0;
      float v1 = sigf(acc1[r] + bg1v1 + c2b) * wg2v1;
      float part = v0 + v1;
      part += __shfl_xor(part, 1);
      part += __shfl_xor(part, 2);
      part += __shfl_xor(part, 4);
      part += __shfl_xor(part, 8);
      float c3v = (float)wb[e * 104 + 96];
      if (row == 0)
        out[eido[w][e]] = sigf(part + bg2v + sigf(c3v + bc3v));
    }
  }
}

extern "C" void kernel_launch(void* const* d_in, const int* in_sizes, int n_in,
                              void* d_out, int out_size, void* d_ws, size_t ws_size,
                              hipStream_t stream)
{
  const float* x   = (const float*)d_in[0];
  const int*   src = (const int*)d_in[1];
  const int*   dst = (const int*)d_in[2];
  const float* Wn1 = (const float*)d_in[3];
  const float* bn1 = (const float*)d_in[4];
  const float* Wc1 = (const float*)d_in[5];
  const float* bc1 = (const float*)d_in[6];
  const float* Wn2 = (const float*)d_in[7];
  const float* bn2 = (const float*)d_in[8];
  const float* Wc2 = (const float*)d_in[9];
  const float* bc2 = (const float*)d_in[10];
  const float* Wn3 = (const float*)d_in[11];
  const float* bn3 = (const float*)d_in[12];
  const float* Wc3 = (const float*)d_in[13];
  const float* bc3 = (const float*)d_in[14];
  const float* Wg1 = (const float*)d_in[15];
  const float* bg1 = (const float*)d_in[16];
  const float* Wg2 = (const float*)d_in[17];
  const float* bg2 = (const float*)d_in[18];
  float* out = (float*)d_out;

  char* base = (char*)d_ws;
  unsigned* TMP16 = (unsigned*)base; base += (size_t)N_NODES * 32 * 4;   // T16 / H2
  unsigned* X16   = (unsigned*)base; base += (size_t)N_NODES * 32 * 4;
  unsigned* Q2_16 = (unsigned*)base; base += (size_t)N_NODES * 32 * 4;
  unsigned* P1_16 = (unsigned*)base; base += (size_t)N_NODES * 32 * 4;
  unsigned* Q3_16 = (unsigned*)base; base += (size_t)N_NODES * 16 * 4;
  unsigned* P2_16 = (unsigned*)base; base += (size_t)N_NODES * 16 * 4;
  _Float16* P3_16 = (_Float16*)base; base += ((size_t)N_NODES * 2 + 15) / 16 * 16;
  int* rowptr = (int*)base;          base += (size_t)(N_NODES + 1) * 4 + 12;
  uint2* ce   = (uint2*)base;        base += (size_t)N_EDGES * 8;
  uint2* cem  = (uint2*)base;        base += (size_t)N_EDGES * 8;
  unsigned short* col16 = (unsigned short*)base; base += ((size_t)N_EDGES * 2 + 15) / 16 * 16;
  int* histM  = (int*)base;          base += (size_t)FILL_B * NB * 4;
  int* colOff = (int*)base;          base += (size_t)FILL_B * NB * 4;
  int* colTot = (int*)base;          base += (size_t)NB * 4;
  int* bucketBase = (int*)base;      base += (size_t)(NB + 1) * 4 + 12;
  uint4* Wg1f = (uint4*)base;        base += 4 * 64 * 16;
  uint4* Wn1f = (uint4*)base;        base += 16 * 64 * 16;
  uint4* Wn2f = (uint4*)base;        base += 16 * 64 * 16;
  uint4* Wc1f = (uint4*)base;        base += 16 * 64 * 16;
  uint4* Wn3f = (uint4*)base;        base += 4 * 64 * 16;
  uint4* Wc2f = (uint4*)base;        base += 4 * 64 * 16;

  // prep (cvt + hist + frag-pack) and radix CSR build
  prep_kernel<<<CVT_B + FILL_B + 1, 256, 0, stream>>>(x, X16, dst, histM,
      Wn1, Wn2, Wc1, Wn3, Wc2, Wg1, Wn1f, Wn2f, Wc1f, Wn3f, Wc2f, Wg1f);
  scanA1_kernel<<<NB, 256, 0, stream>>>(histM, colOff, colTot);
  scanA2_kernel<<<1, 256, 0, stream>>>(colTot, bucketBase);
  fill2_kernel<<<FILL_B, 256, 0, stream>>>(src, dst, colOff, bucketBase, cem);
  fill3_kernel<<<NB, 256, 0, stream>>>(cem, bucketBase, ce, col16, rowptr);

  // layer 1: T16 = x + agg(x); node1 -> Q2, P1
  gather1_kernel<<<(N_NODES + 3) / 4, 256, 0, stream>>>(X16, rowptr, col16, TMP16);
  node1_kernel<<<NODE_B, 256, 0, stream>>>(TMP16, Wn1f, Wn2f, Wc1f, bn1,
      (_Float16*)Q2_16, (_Float16*)P1_16);
  // layer 2: H2 = sig(Q2 + agg(Q2) + bn2); node2 -> Q3, P2
  gather2_kernel<<<(N_NODES + 3) / 4, 256, 0, stream>>>(Q2_16, rowptr, col16, bn2, TMP16);
  node2_kernel<<<NODE_B, 256, 0, stream>>>(TMP16, Wn3f, Wc2f,
      (_Float16*)Q3_16, (_Float16*)P2_16);
  // layer 3 (gather + node3 fused) -> P3
  gather3_kernel<<<(N_NODES + 3) / 4, 256, 0, stream>>>(Q3_16, rowptr, col16, bn3, Wc3, P3_16);
  // edge-level epilogue in CSR (dst-sorted) order, 2-wave blocks
  edge_kernel<<<EDGE_B2, 128, 0, stream>>>(ce, P1_16, P2_16, P3_16, Wg1f,
      bc1, bc2, bc3, bg1, Wg2, bg2, out);
}